// Round 6
// baseline (269.845 us; speedup 1.0000x reference)
//
#include <hip/hip_runtime.h>
#include <hip/hip_bf16.h>
#include <math.h>

#define NN 32768
#define LL 33
#define DD 128
#define EE 131072

typedef short bf16x8 __attribute__((ext_vector_type(8)));
typedef float f32x4 __attribute__((ext_vector_type(4)));

__device__ inline unsigned short f2bf(float f) {
  __hip_bfloat16 h = __float2bfloat16(f);
  return *reinterpret_cast<unsigned short*>(&h);
}
__device__ inline float bf2f(unsigned short u) {
  return __uint_as_float(((unsigned int)u) << 16);
}
// async global->LDS, 16B per lane. LDS dest is wave-uniform base + lane*16;
// global src is per-lane (we pre-swizzle the SOURCE so LDS stays linear).
__device__ inline void gload16(const void* g, void* lds) {
  __builtin_amdgcn_global_load_lds(
      (const __attribute__((address_space(1))) unsigned int*)g,
      (__attribute__((address_space(3))) unsigned int*)lds, 16, 0, 0);
}

// ---------------------------------------------------------------------------
// Parallel mask-layout detect. Reads the first NN*LL bytes (safe under both
// layouts) as dwords; a nonzero byte at p%4!=0 <=> (dword & 0xFFFFFF00) != 0
// <=> byte-layout mask. flag must be zeroed beforehand (hipMemsetAsync).
// ---------------------------------------------------------------------------
__global__ __launch_bounds__(256) void detect_mask_kernel(
    const unsigned int* __restrict__ mw, int* __restrict__ flag) {
  const int nd = NN * LL / 4;
  int found = 0;
  for (int p = blockIdx.x * 256 + threadIdx.x; p < nd; p += gridDim.x * 256) {
    if (mw[p] & 0xFFFFFF00u) found = 1;
  }
  __shared__ int s;
  if (threadIdx.x == 0) s = 0;
  __syncthreads();
  if (found) atomicOr(&s, 1);
  __syncthreads();
  if (threadIdx.x == 0 && s) atomicOr(flag, 1);
}

__global__ __launch_bounds__(256) void lengths_kernel(
    const unsigned char* __restrict__ mb, const int* __restrict__ flag,
    int* __restrict__ lengths) {
  const int i = blockIdx.x * 256 + threadIdx.x;
  if (i >= NN) return;
  const int esz = (*flag) ? 1 : 4;
  int len = LL;
  for (int j = 1; j < LL; ++j) {
    if (mb[(size_t)(i * LL + j) * esz] != 0) { len = j; break; }
  }
  lengths[i] = len;
}

// ---------------------------------------------------------------------------
// prep: fp32 weights -> bf16 copies (with K-padding where needed)
// ---------------------------------------------------------------------------
__global__ __launch_bounds__(256) void prep_weights(
    const float* __restrict__ qkvw, const float* __restrict__ outw,
    const float* __restrict__ projw, const float* __restrict__ w1,
    const float* __restrict__ w2,
    unsigned short* __restrict__ qkvwbf, unsigned short* __restrict__ outwbf,
    unsigned short* __restrict__ projwbf, unsigned short* __restrict__ w1xbf,
    unsigned short* __restrict__ w2bf) {
  int i = blockIdx.x * 256 + threadIdx.x;
  const int n_qkv = 3 * 384 * 128, n_out = 3 * 128 * 128;
  const int n_proj = 128 * 192, n_w1 = 128 * 256, n_w2 = 128 * 128;
  if (i < n_qkv) { qkvwbf[i] = f2bf(qkvw[i]); return; }
  i -= n_qkv;
  if (i < n_out) { outwbf[i] = f2bf(outw[i]); return; }
  i -= n_out;
  if (i < n_proj) {
    int n = i / 192, c = i - n * 192;
    projwbf[i] = f2bf(c < 160 ? projw[n * 160 + c] : 0.f);
    return;
  }
  i -= n_proj;
  if (i < n_w1) {
    int n = i / 256, c = i - n * 256;
    w1xbf[i] = f2bf(w1[n * 258 + c]);
    return;
  }
  i -= n_w1;
  if (i < n_w2) w2bf[i] = f2bf(w2[i]);
}

// ---------------------------------------------------------------------------
// feat_build: bf16 feature matrix [NN][192]
// ---------------------------------------------------------------------------
__global__ __launch_bounds__(256) void feat_build(
    const int* __restrict__ ti, const int* __restrict__ ci,
    const float* __restrict__ ldg, const float* __restrict__ temb,
    const float* __restrict__ c0, const float* __restrict__ c1,
    const float* __restrict__ dw, const float* __restrict__ db,
    unsigned short* __restrict__ feat) {
  const int i = blockIdx.x * 256 + threadIdx.x;
  if (i >= NN * 192) return;
  const int n = i / 192, c = i - n * 192;
  float v;
  if (c < 64)       v = temb[(size_t)ti[n] * 64 + c];
  else if (c < 96)  v = c0[(size_t)ci[2 * n] * 32 + (c - 64)];
  else if (c < 128) v = c1[(size_t)ci[2 * n + 1] * 32 + (c - 96)];
  else if (c < 160) v = fmaxf(fmaf(ldg[n], dw[c - 128], db[c - 128]), 0.f);
  else              v = 0.f;
  feat[i] = f2bf(v);
}

// ---------------------------------------------------------------------------
// bf16 MFMA GEMM: C[M,NO] = act(A @ W^T + bias), 128x128 tile, BK=64.
// seg != 0: y-block outputs go to planar segments C + y*seg (local col).
// ---------------------------------------------------------------------------
__global__ __launch_bounds__(256) void mfma_gemm(
    const char* __restrict__ A, int a_rs, const char* __restrict__ W, int w_rs,
    const float* __restrict__ bias, int nsteps, int relu,
    unsigned short* __restrict__ C, int c_rs, size_t seg) {
  __shared__ char As[16384];
  __shared__ char Bs[16384];
  const int t = threadIdx.x, l = t & 63, w = t >> 6;
  const int bm = blockIdx.x * 128, bn = blockIdx.y * 128;
  const int wr = w >> 1, wc = w & 1;
  f32x4 acc[4][4];
#pragma unroll
  for (int mi = 0; mi < 4; ++mi)
#pragma unroll
    for (int ni = 0; ni < 4; ++ni)
#pragma unroll
      for (int j = 0; j < 4; ++j) acc[mi][ni][j] = 0.f;

  for (int ks = 0; ks < nsteps; ++ks) {
#pragma unroll
    for (int i = 0; i < 4; ++i) {
      const int row = w * 32 + i * 8 + (l >> 3);
      const int ch = (l & 7) ^ (row & 7);
      gload16(A + (size_t)(bm + row) * a_rs + ks * 128 + ch * 16,
              As + w * 4096 + i * 1024);
      gload16(W + (size_t)(bn + row) * w_rs + ks * 128 + ch * 16,
              Bs + w * 4096 + i * 1024);
    }
    __syncthreads();
#pragma unroll
    for (int k0 = 0; k0 < 2; ++k0) {
      bf16x8 af[4], bff[4];
#pragma unroll
      for (int mi = 0; mi < 4; ++mi) {
        const int r = wr * 64 + mi * 16 + (l & 15);
        const int off = (k0 * 64 + (l >> 4) * 16) ^ ((r & 7) << 4);
        af[mi] = *(const bf16x8*)(As + r * 128 + off);
      }
#pragma unroll
      for (int ni = 0; ni < 4; ++ni) {
        const int r = wc * 64 + ni * 16 + (l & 15);
        const int off = (k0 * 64 + (l >> 4) * 16) ^ ((r & 7) << 4);
        bff[ni] = *(const bf16x8*)(Bs + r * 128 + off);
      }
#pragma unroll
      for (int mi = 0; mi < 4; ++mi)
#pragma unroll
        for (int ni = 0; ni < 4; ++ni)
          acc[mi][ni] = __builtin_amdgcn_mfma_f32_16x16x32_bf16(
              af[mi], bff[ni], acc[mi][ni], 0, 0, 0);
    }
    __syncthreads();
  }
  unsigned short* Cw = C;
  int coloff = bn;
  if (seg) { Cw = C + (size_t)blockIdx.y * seg; coloff = 0; }
#pragma unroll
  for (int ni = 0; ni < 4; ++ni) {
    const int lc = wc * 64 + ni * 16 + (l & 15);
    const float bz = bias[bn + lc];
    const int col = coloff + lc;
#pragma unroll
    for (int mi = 0; mi < 4; ++mi)
#pragma unroll
      for (int j = 0; j < 4; ++j) {
        const int row = bm + wr * 64 + mi * 16 + (l >> 4) * 4 + j;
        float v = acc[mi][ni][j] + bz;
        if (relu) v = fmaxf(v, 0.f);
        Cw[(size_t)row * c_rs + col] = f2bf(v);
      }
  }
}

// ---------------------------------------------------------------------------
// Attention, planar Q/K/V [N][128] bf16, single-pass softmax with fixed
// shift s0 = score(neighbor 0) (exact: softmax is shift-invariant; removes
// the loop-carried max/rescale chain -> 1 exp + 3 indep FMA chains per c).
// Persistent waves: 2048 blocks x 4 waves, each wave exactly 4 nodes.
// ---------------------------------------------------------------------------
__global__ __launch_bounds__(256) void attn_kernel(
    const unsigned short* __restrict__ Q, const unsigned short* __restrict__ K,
    const unsigned short* __restrict__ V, const int* __restrict__ ctx,
    const int* __restrict__ lengths, unsigned short* __restrict__ O) {
  __shared__ int s_idx[4][36];
  const int t = threadIdx.x, w = t >> 6, lane = t & 63;
  for (int node = blockIdx.x * 4 + w; node < NN; node += gridDim.x * 4) {
    const int len = lengths[node];
    if (lane < LL) s_idx[w][lane] = ctx[(size_t)node * LL + lane];
    __builtin_amdgcn_wave_barrier();   // per-wave LDS slot; no block barrier
    const unsigned int qu = *(const unsigned int*)(Q + (size_t)node * 128 + 2 * lane);
    const float qx = bf2f((unsigned short)qu) * 0.17677669529663687f;  // /sqrt(32)
    const float qy = bf2f((unsigned short)(qu >> 16)) * 0.17677669529663687f;
    // neighbor 0 (always valid, self): defines the shift s0; e0 = 1.
    const int ki0 = s_idx[w][0];
    const unsigned int ku0 = *(const unsigned int*)(K + (size_t)ki0 * 128 + 2 * lane);
    const unsigned int vu0 = *(const unsigned int*)(V + (size_t)ki0 * 128 + 2 * lane);
    float part = qx * bf2f((unsigned short)ku0) +
                 qy * bf2f((unsigned short)(ku0 >> 16));
    part += __shfl_xor(part, 1);
    part += __shfl_xor(part, 2);
    part += __shfl_xor(part, 4);
    part += __shfl_xor(part, 8);
    const float s0 = part;             // per-head (16-lane groups)
    float ssum = 1.f;
    float ax = bf2f((unsigned short)vu0), ay = bf2f((unsigned short)(vu0 >> 16));
    for (int l0 = 1; l0 < len; l0 += 4) {
      unsigned int ku[4], vu[4];
      int okc[4];
#pragma unroll
      for (int c = 0; c < 4; ++c) {
        const int lc = l0 + c;
        const int ok = lc < len;
        okc[c] = ok;
        const int ki = s_idx[w][ok ? lc : 0];
        ku[c] = *(const unsigned int*)(K + (size_t)ki * 128 + 2 * lane);
        vu[c] = *(const unsigned int*)(V + (size_t)ki * 128 + 2 * lane);
      }
#pragma unroll
      for (int c = 0; c < 4; ++c) {
        float p2 = qx * bf2f((unsigned short)ku[c]) +
                   qy * bf2f((unsigned short)(ku[c] >> 16));
        p2 += __shfl_xor(p2, 1);
        p2 += __shfl_xor(p2, 2);
        p2 += __shfl_xor(p2, 4);
        p2 += __shfl_xor(p2, 8);
        const float e = okc[c] ? __expf(p2 - s0) : 0.f;
        ssum += e;
        ax = fmaf(e, bf2f((unsigned short)vu[c]), ax);
        ay = fmaf(e, bf2f((unsigned short)(vu[c] >> 16)), ay);
      }
    }
    const float inv = 1.f / ssum;
    const unsigned int ou =
        ((unsigned int)f2bf(ay * inv) << 16) | f2bf(ax * inv);
    *(unsigned int*)(O + (size_t)node * DD + 2 * lane) = ou;
  }
}

// ---------------------------------------------------------------------------
// Fused edge MLP, 128 edges/block, all-MFMA (unchanged).
// ---------------------------------------------------------------------------
__global__ __launch_bounds__(256) void edge_fused(
    const char* __restrict__ xbf, const int* __restrict__ eu,
    const int* __restrict__ ev, const float* __restrict__ ef,
    const char* __restrict__ w1x, const float* __restrict__ w1f,
    const float* __restrict__ b1, const char* __restrict__ w2,
    const float* __restrict__ b2, const float* __restrict__ w3,
    const float* __restrict__ b3, float* __restrict__ out) {
  __shared__ char lds[65536];
  char* As = lds;
  char* Bs = lds + 16384;
  char* H1 = lds + 32768;
  float* s_part = (float*)lds;
  const int t = threadIdx.x, l = t & 63, w = t >> 6;
  const int bm = blockIdx.x * 128;
  const int wr = w >> 1, wc = w & 1;
  f32x4 acc[4][4];
#pragma unroll
  for (int mi = 0; mi < 4; ++mi)
#pragma unroll
    for (int ni = 0; ni < 4; ++ni)
#pragma unroll
      for (int j = 0; j < 4; ++j) acc[mi][ni][j] = 0.f;

  for (int ks = 0; ks < 4; ++ks) {
    const int* idxp = (ks < 2) ? eu : ev;
#pragma unroll
    for (int i = 0; i < 4; ++i) {
      const int row = w * 32 + i * 8 + (l >> 3);
      const int ch = (l & 7) ^ (row & 7);
      const int nidx = idxp[bm + row];
      gload16(xbf + (size_t)nidx * 256 + (ks & 1) * 128 + ch * 16,
              As + w * 4096 + i * 1024);
      gload16(w1x + (size_t)row * 512 + ks * 128 + ch * 16,
              Bs + w * 4096 + i * 1024);
    }
    __syncthreads();
#pragma unroll
    for (int k0 = 0; k0 < 2; ++k0) {
      bf16x8 af[4], bff[4];
#pragma unroll
      for (int mi = 0; mi < 4; ++mi) {
        const int r = wr * 64 + mi * 16 + (l & 15);
        const int off = (k0 * 64 + (l >> 4) * 16) ^ ((r & 7) << 4);
        af[mi] = *(const bf16x8*)(As + r * 128 + off);
      }
#pragma unroll
      for (int ni = 0; ni < 4; ++ni) {
        const int r = wc * 64 + ni * 16 + (l & 15);
        const int off = (k0 * 64 + (l >> 4) * 16) ^ ((r & 7) << 4);
        bff[ni] = *(const bf16x8*)(Bs + r * 128 + off);
      }
#pragma unroll
      for (int mi = 0; mi < 4; ++mi)
#pragma unroll
        for (int ni = 0; ni < 4; ++ni)
          acc[mi][ni] = __builtin_amdgcn_mfma_f32_16x16x32_bf16(
              af[mi], bff[ni], acc[mi][ni], 0, 0, 0);
    }
    __syncthreads();
  }
  float w1c0[4], w1c1[4], bb[4];
#pragma unroll
  for (int ni = 0; ni < 4; ++ni) {
    const int col = wc * 64 + ni * 16 + (l & 15);
    w1c0[ni] = w1f[col * 258 + 256];
    w1c1[ni] = w1f[col * 258 + 257];
    bb[ni] = b1[col];
  }
#pragma unroll
  for (int mi = 0; mi < 4; ++mi)
#pragma unroll
    for (int j = 0; j < 4; ++j) {
      const int rl = wr * 64 + mi * 16 + (l >> 4) * 4 + j;
      const float2 e2 = *(const float2*)(ef + 2 * (size_t)(bm + rl));
#pragma unroll
      for (int ni = 0; ni < 4; ++ni) {
        float v = acc[mi][ni][j] + e2.x * w1c0[ni] + e2.y * w1c1[ni] + bb[ni];
        v = fmaxf(v, 0.f);
        const int col = wc * 64 + ni * 16 + (l & 15);
        const int off = (col * 2) ^ ((rl & 7) << 4);
        *(unsigned short*)(H1 + rl * 256 + off) = f2bf(v);
      }
    }
  __syncthreads();
  f32x4 acc2[4][4];
#pragma unroll
  for (int mi = 0; mi < 4; ++mi)
#pragma unroll
    for (int ni = 0; ni < 4; ++ni)
#pragma unroll
      for (int j = 0; j < 4; ++j) acc2[mi][ni][j] = 0.f;
  for (int ks2 = 0; ks2 < 2; ++ks2) {
#pragma unroll
    for (int i = 0; i < 4; ++i) {
      const int row = w * 32 + i * 8 + (l >> 3);
      const int ch = (l & 7) ^ (row & 7);
      gload16(w2 + (size_t)row * 256 + ks2 * 128 + ch * 16,
              Bs + w * 4096 + i * 1024);
    }
    __syncthreads();
#pragma unroll
    for (int k0 = 0; k0 < 2; ++k0) {
      bf16x8 af[4], bff[4];
#pragma unroll
      for (int mi = 0; mi < 4; ++mi) {
        const int r = wr * 64 + mi * 16 + (l & 15);
        const int off = (ks2 * 128 + k0 * 64 + (l >> 4) * 16) ^ ((r & 7) << 4);
        af[mi] = *(const bf16x8*)(H1 + r * 256 + off);
      }
#pragma unroll
      for (int ni = 0; ni < 4; ++ni) {
        const int r = wc * 64 + ni * 16 + (l & 15);
        const int off = (k0 * 64 + (l >> 4) * 16) ^ ((r & 7) << 4);
        bff[ni] = *(const bf16x8*)(Bs + r * 128 + off);
      }
#pragma unroll
      for (int mi = 0; mi < 4; ++mi)
#pragma unroll
        for (int ni = 0; ni < 4; ++ni)
          acc2[mi][ni] = __builtin_amdgcn_mfma_f32_16x16x32_bf16(
              af[mi], bff[ni], acc2[mi][ni], 0, 0, 0);
    }
    __syncthreads();
  }
  float b2v[4], w3v[4];
#pragma unroll
  for (int ni = 0; ni < 4; ++ni) {
    const int col = wc * 64 + ni * 16 + (l & 15);
    b2v[ni] = b2[col];
    w3v[ni] = w3[col];
  }
#pragma unroll
  for (int mi = 0; mi < 4; ++mi)
#pragma unroll
    for (int j = 0; j < 4; ++j) {
      const int rl = wr * 64 + mi * 16 + (l >> 4) * 4 + j;
      float p = 0.f;
#pragma unroll
      for (int ni = 0; ni < 4; ++ni) {
        const float h2 = fmaxf(acc2[mi][ni][j] + b2v[ni], 0.f);
        p = fmaf(h2, w3v[ni], p);
      }
      p += __shfl_xor(p, 1);
      p += __shfl_xor(p, 2);
      p += __shfl_xor(p, 4);
      p += __shfl_xor(p, 8);
      if ((l & 15) == 0) s_part[wc * 128 + rl] = p;
    }
  __syncthreads();
  if (t < 128) out[bm + t] = s_part[t] + s_part[128 + t] + b3[0];
}

// ---------------------------------------------------------------------------
extern "C" void kernel_launch(void* const* d_in, const int* in_sizes, int n_in,
                              void* d_out, int out_size, void* d_ws, size_t ws_size,
                              hipStream_t stream) {
  (void)in_sizes; (void)n_in; (void)out_size; (void)ws_size;
  const int*   type_idx   = (const int*)d_in[0];
  const int*   cat_idx    = (const int*)d_in[1];
  const float* log_degree = (const float*)d_in[2];
  const int*   ctx        = (const int*)d_in[3];
  const unsigned char* mask = (const unsigned char*)d_in[4];
  const int*   eu         = (const int*)d_in[5];
  const int*   ev         = (const int*)d_in[6];
  const float* ef         = (const float*)d_in[7];
  const float* type_embed = (const float*)d_in[8];
  const float* cat0       = (const float*)d_in[9];
  const float* cat1       = (const float*)d_in[10];
  const float* dw         = (const float*)d_in[11];
  const float* db         = (const float*)d_in[12];
  const float* proj_w     = (const float*)d_in[13];
  const float* proj_b     = (const float*)d_in[14];
  const float* qkv_w      = (const float*)d_in[15];
  const float* qkv_b      = (const float*)d_in[16];
  const float* out_w      = (const float*)d_in[17];
  const float* out_b      = (const float*)d_in[18];
  const float* w1         = (const float*)d_in[19];
  const float* b1         = (const float*)d_in[20];
  const float* w2         = (const float*)d_in[21];
  const float* b2         = (const float*)d_in[22];
  const float* w3         = (const float*)d_in[23];
  const float* b3         = (const float*)d_in[24];

  char* ws = (char*)d_ws;
  char* xbf     = ws;                       // [N][128] bf16   8 MB
  char* qkvbf   = ws + 8388608;             // [3][N][128] bf16 24 MB (planar)
  char* obf     = ws + 33554432;            // [N][128] bf16   8 MB
  char* featbf  = ws + 41943040;            // [N][192] bf16   12 MB
  char* qkvwbf  = ws + 54525952;            // 3*384*128 bf16
  char* outwbf  = ws + 54820864;            // 3*128*128 bf16
  char* projwbf = ws + 54919168;            // 128*192 bf16
  char* w1xbf   = ws + 54968320;            // 128*256 bf16
  char* w2bf    = ws + 55033856;            // 128*128 bf16
  int*  lengths = (int*)(ws + 55066624);
  int*  flag    = (int*)(ws + 55197696);

  hipMemsetAsync(flag, 0, sizeof(int), stream);
  detect_mask_kernel<<<256, 256, 0, stream>>>((const unsigned int*)mask, flag);
  lengths_kernel<<<NN / 256, 256, 0, stream>>>(mask, flag, lengths);

  prep_weights<<<1056, 256, 0, stream>>>(
      qkv_w, out_w, proj_w, w1, w2,
      (unsigned short*)qkvwbf, (unsigned short*)outwbf,
      (unsigned short*)projwbf, (unsigned short*)w1xbf, (unsigned short*)w2bf);
  feat_build<<<NN * 192 / 256, 256, 0, stream>>>(
      type_idx, cat_idx, log_degree, type_embed, cat0, cat1, dw, db,
      (unsigned short*)featbf);

  // encode: x = feat[192] @ projw^T + proj_b (no relu)
  mfma_gemm<<<dim3(NN / 128, 1), 256, 0, stream>>>(
      featbf, 384, projwbf, 384, proj_b, 3, 0, (unsigned short*)xbf, 128, 0);

  const size_t seg = (size_t)NN * 128;  // planar Q/K/V segment (elements)
  unsigned short* Qp = (unsigned short*)qkvbf;
  unsigned short* Kp = Qp + seg;
  unsigned short* Vp = Kp + seg;
  for (int layer = 0; layer < 3; ++layer) {
    mfma_gemm<<<dim3(NN / 128, 3), 256, 0, stream>>>(
        xbf, 256, qkvwbf + (size_t)layer * 98304, 256,
        qkv_b + (size_t)layer * 384, 2, 0, Qp, 128, seg);
    attn_kernel<<<2048, 256, 0, stream>>>(
        Qp, Kp, Vp, ctx, lengths, (unsigned short*)obf);
    mfma_gemm<<<dim3(NN / 128, 1), 256, 0, stream>>>(
        obf, 256, outwbf + (size_t)layer * 32768, 256,
        out_b + (size_t)layer * 128, 2, 1, (unsigned short*)xbf, 128, 0);
  }

  edge_fused<<<EE / 128, 256, 0, stream>>>(
      xbf, eu, ev, ef, w1xbf, w1, b1, w2bf, b2, w3, b3, (float*)d_out);
}

// Round 7
// 246.947 us; speedup vs baseline: 1.0927x; 1.0927x over previous
//
#include <hip/hip_runtime.h>
#include <hip/hip_bf16.h>
#include <math.h>

#define NN 32768
#define LL 33
#define DD 128
#define EE 131072

typedef short bf16x8 __attribute__((ext_vector_type(8)));
typedef float f32x4 __attribute__((ext_vector_type(4)));

__device__ inline unsigned short f2bf(float f) {
  __hip_bfloat16 h = __float2bfloat16(f);
  return *reinterpret_cast<unsigned short*>(&h);
}
__device__ inline float bf2f(unsigned short u) {
  return __uint_as_float(((unsigned int)u) << 16);
}
// async global->LDS, 16B per lane. LDS dest is wave-uniform base + lane*16;
// global src is per-lane (we pre-swizzle the SOURCE so LDS stays linear).
__device__ inline void gload16(const void* g, void* lds) {
  __builtin_amdgcn_global_load_lds(
      (const __attribute__((address_space(1))) unsigned int*)g,
      (__attribute__((address_space(3))) unsigned int*)lds, 16, 0, 0);
}

// ---------------------------------------------------------------------------
// Parallel mask-layout detect (dword scan; see round-4 notes).
// ---------------------------------------------------------------------------
__global__ __launch_bounds__(256) void detect_mask_kernel(
    const unsigned int* __restrict__ mw, int* __restrict__ flag) {
  const int nd = NN * LL / 4;
  int found = 0;
  for (int p = blockIdx.x * 256 + threadIdx.x; p < nd; p += gridDim.x * 256) {
    if (mw[p] & 0xFFFFFF00u) found = 1;
  }
  __shared__ int s;
  if (threadIdx.x == 0) s = 0;
  __syncthreads();
  if (found) atomicOr(&s, 1);
  __syncthreads();
  if (threadIdx.x == 0 && s) atomicOr(flag, 1);
}

__global__ __launch_bounds__(256) void lengths_kernel(
    const unsigned char* __restrict__ mb, const int* __restrict__ flag,
    int* __restrict__ lengths) {
  const int i = blockIdx.x * 256 + threadIdx.x;
  if (i >= NN) return;
  const int esz = (*flag) ? 1 : 4;
  int len = LL;
  for (int j = 1; j < LL; ++j) {
    if (mb[(size_t)(i * LL + j) * esz] != 0) { len = j; break; }
  }
  lengths[i] = len;
}

// ---------------------------------------------------------------------------
// prep: fp32 weights -> bf16 copies (with K-padding where needed)
// ---------------------------------------------------------------------------
__global__ __launch_bounds__(256) void prep_weights(
    const float* __restrict__ qkvw, const float* __restrict__ outw,
    const float* __restrict__ projw, const float* __restrict__ w1,
    const float* __restrict__ w2,
    unsigned short* __restrict__ qkvwbf, unsigned short* __restrict__ outwbf,
    unsigned short* __restrict__ projwbf, unsigned short* __restrict__ w1xbf,
    unsigned short* __restrict__ w2bf) {
  int i = blockIdx.x * 256 + threadIdx.x;
  const int n_qkv = 3 * 384 * 128, n_out = 3 * 128 * 128;
  const int n_proj = 128 * 192, n_w1 = 128 * 256, n_w2 = 128 * 128;
  if (i < n_qkv) { qkvwbf[i] = f2bf(qkvw[i]); return; }
  i -= n_qkv;
  if (i < n_out) { outwbf[i] = f2bf(outw[i]); return; }
  i -= n_out;
  if (i < n_proj) {
    int n = i / 192, c = i - n * 192;
    projwbf[i] = f2bf(c < 160 ? projw[n * 160 + c] : 0.f);
    return;
  }
  i -= n_proj;
  if (i < n_w1) {
    int n = i / 256, c = i - n * 256;
    w1xbf[i] = f2bf(w1[n * 258 + c]);
    return;
  }
  i -= n_w1;
  if (i < n_w2) w2bf[i] = f2bf(w2[i]);
}

// ---------------------------------------------------------------------------
// feat_build: bf16 feature matrix [NN][192]
// ---------------------------------------------------------------------------
__global__ __launch_bounds__(256) void feat_build(
    const int* __restrict__ ti, const int* __restrict__ ci,
    const float* __restrict__ ldg, const float* __restrict__ temb,
    const float* __restrict__ c0, const float* __restrict__ c1,
    const float* __restrict__ dw, const float* __restrict__ db,
    unsigned short* __restrict__ feat) {
  const int i = blockIdx.x * 256 + threadIdx.x;
  if (i >= NN * 192) return;
  const int n = i / 192, c = i - n * 192;
  float v;
  if (c < 64)       v = temb[(size_t)ti[n] * 64 + c];
  else if (c < 96)  v = c0[(size_t)ci[2 * n] * 32 + (c - 64)];
  else if (c < 128) v = c1[(size_t)ci[2 * n + 1] * 32 + (c - 96)];
  else if (c < 160) v = fmaxf(fmaf(ldg[n], dw[c - 128], db[c - 128]), 0.f);
  else              v = 0.f;
  feat[i] = f2bf(v);
}

// ---------------------------------------------------------------------------
// bf16 MFMA GEMM: C[M,NO] = act(A @ W^T + bias), 128x128 tile, BK=64.
// seg != 0: y-block outputs go to planar segments C + y*seg (local col).
// ---------------------------------------------------------------------------
__global__ __launch_bounds__(256) void mfma_gemm(
    const char* __restrict__ A, int a_rs, const char* __restrict__ W, int w_rs,
    const float* __restrict__ bias, int nsteps, int relu,
    unsigned short* __restrict__ C, int c_rs, size_t seg) {
  __shared__ char As[16384];
  __shared__ char Bs[16384];
  const int t = threadIdx.x, l = t & 63, w = t >> 6;
  const int bm = blockIdx.x * 128, bn = blockIdx.y * 128;
  const int wr = w >> 1, wc = w & 1;
  f32x4 acc[4][4];
#pragma unroll
  for (int mi = 0; mi < 4; ++mi)
#pragma unroll
    for (int ni = 0; ni < 4; ++ni)
#pragma unroll
      for (int j = 0; j < 4; ++j) acc[mi][ni][j] = 0.f;

  for (int ks = 0; ks < nsteps; ++ks) {
#pragma unroll
    for (int i = 0; i < 4; ++i) {
      const int row = w * 32 + i * 8 + (l >> 3);
      const int ch = (l & 7) ^ (row & 7);
      gload16(A + (size_t)(bm + row) * a_rs + ks * 128 + ch * 16,
              As + w * 4096 + i * 1024);
      gload16(W + (size_t)(bn + row) * w_rs + ks * 128 + ch * 16,
              Bs + w * 4096 + i * 1024);
    }
    __syncthreads();
#pragma unroll
    for (int k0 = 0; k0 < 2; ++k0) {
      bf16x8 af[4], bff[4];
#pragma unroll
      for (int mi = 0; mi < 4; ++mi) {
        const int r = wr * 64 + mi * 16 + (l & 15);
        const int off = (k0 * 64 + (l >> 4) * 16) ^ ((r & 7) << 4);
        af[mi] = *(const bf16x8*)(As + r * 128 + off);
      }
#pragma unroll
      for (int ni = 0; ni < 4; ++ni) {
        const int r = wc * 64 + ni * 16 + (l & 15);
        const int off = (k0 * 64 + (l >> 4) * 16) ^ ((r & 7) << 4);
        bff[ni] = *(const bf16x8*)(Bs + r * 128 + off);
      }
#pragma unroll
      for (int mi = 0; mi < 4; ++mi)
#pragma unroll
        for (int ni = 0; ni < 4; ++ni)
          acc[mi][ni] = __builtin_amdgcn_mfma_f32_16x16x32_bf16(
              af[mi], bff[ni], acc[mi][ni], 0, 0, 0);
    }
    __syncthreads();
  }
  unsigned short* Cw = C;
  int coloff = bn;
  if (seg) { Cw = C + (size_t)blockIdx.y * seg; coloff = 0; }
#pragma unroll
  for (int ni = 0; ni < 4; ++ni) {
    const int lc = wc * 64 + ni * 16 + (l & 15);
    const float bz = bias[bn + lc];
    const int col = coloff + lc;
#pragma unroll
    for (int mi = 0; mi < 4; ++mi)
#pragma unroll
      for (int j = 0; j < 4; ++j) {
        const int row = bm + wr * 64 + mi * 16 + (l >> 4) * 4 + j;
        float v = acc[mi][ni][j] + bz;
        if (relu) v = fmaxf(v, 0.f);
        Cw[(size_t)row * c_rs + col] = f2bf(v);
      }
  }
}

// ---------------------------------------------------------------------------
// Attention, planar Q/K/V [N][128] bf16. Quad-parallel layout:
// lane = (q4=lane>>4, s=lane&15); 16 lanes x 8 dims cover a row; the 4 quads
// process 4 neighbors concurrently (4x fewer serial rounds, 16B loads).
// Head h = s>>2 (32 dims = 4 lanes); score reduce = 2 shfl; softmax unshifted
// (exact; scores O(1)). Quad partials combined via xor-16/32 butterflies.
// One-ahead software pipeline (len is wave-uniform).
// ---------------------------------------------------------------------------
__global__ __launch_bounds__(256) void attn_kernel(
    const unsigned short* __restrict__ Q, const unsigned short* __restrict__ K,
    const unsigned short* __restrict__ V, const int* __restrict__ ctx,
    const int* __restrict__ lengths, unsigned short* __restrict__ O) {
  const int t = threadIdx.x, w = t >> 6, lane = t & 63;
  const int node = blockIdx.x * 4 + w;
  const int q4 = lane >> 4, s = lane & 15;
  const int len = lengths[node];
  const int idxv = ctx[(size_t)node * LL + (lane < LL ? lane : 0)];
  const bf16x8 qv = *(const bf16x8*)(Q + (size_t)node * 128 + s * 8);
  float qf[8];
#pragma unroll
  for (int j = 0; j < 8; ++j)
    qf[j] = bf2f((unsigned short)qv[j]) * 0.17677669529663687f;  // /sqrt(32)
  float av[8];
#pragma unroll
  for (int j = 0; j < 8; ++j) av[j] = 0.f;
  float ssum = 0.f;

  int ok = q4 < len;
  int ki = __shfl(idxv, ok ? q4 : 0);
  bf16x8 kv = *(const bf16x8*)(K + (size_t)ki * 128 + s * 8);
  bf16x8 vv = *(const bf16x8*)(V + (size_t)ki * 128 + s * 8);

  for (int l0 = 0; l0 < len; l0 += 4) {
    // prefetch next group (wave-uniform guard)
    const int posn = l0 + 4 + q4;
    const int okn = posn < len;
    const int kin = __shfl(idxv, okn ? posn : 0);
    bf16x8 kvn = kv, vvn = vv;
    if (l0 + 4 < len) {
      kvn = *(const bf16x8*)(K + (size_t)kin * 128 + s * 8);
      vvn = *(const bf16x8*)(V + (size_t)kin * 128 + s * 8);
    }
    // score for this quad's neighbor
    float sc = 0.f;
#pragma unroll
    for (int j = 0; j < 8; ++j)
      sc = fmaf(qf[j], bf2f((unsigned short)kv[j]), sc);
    sc += __shfl_xor(sc, 1);
    sc += __shfl_xor(sc, 2);
    const float e = ok ? __expf(sc) : 0.f;
    ssum += e;
#pragma unroll
    for (int j = 0; j < 8; ++j)
      av[j] = fmaf(e, bf2f((unsigned short)vv[j]), av[j]);
    kv = kvn; vv = vvn; ok = okn;
  }
  // combine the 4 quads (lane bits 4,5)
#pragma unroll
  for (int j = 0; j < 8; ++j) {
    av[j] += __shfl_xor(av[j], 16);
    av[j] += __shfl_xor(av[j], 32);
  }
  ssum += __shfl_xor(ssum, 16);
  ssum += __shfl_xor(ssum, 32);
  if (q4 == 0) {
    const float inv = 1.f / ssum;
    unsigned int o[4];
#pragma unroll
    for (int p = 0; p < 4; ++p)
      o[p] = (unsigned int)f2bf(av[2 * p] * inv) |
             ((unsigned int)f2bf(av[2 * p + 1] * inv) << 16);
    *(uint4*)(O + (size_t)node * DD + s * 8) =
        make_uint4(o[0], o[1], o[2], o[3]);
  }
}

// ---------------------------------------------------------------------------
// Fused edge MLP, 128 edges/block, all-MFMA (unchanged).
// ---------------------------------------------------------------------------
__global__ __launch_bounds__(256) void edge_fused(
    const char* __restrict__ xbf, const int* __restrict__ eu,
    const int* __restrict__ ev, const float* __restrict__ ef,
    const char* __restrict__ w1x, const float* __restrict__ w1f,
    const float* __restrict__ b1, const char* __restrict__ w2,
    const float* __restrict__ b2, const float* __restrict__ w3,
    const float* __restrict__ b3, float* __restrict__ out) {
  __shared__ char lds[65536];
  char* As = lds;
  char* Bs = lds + 16384;
  char* H1 = lds + 32768;
  float* s_part = (float*)lds;
  const int t = threadIdx.x, l = t & 63, w = t >> 6;
  const int bm = blockIdx.x * 128;
  const int wr = w >> 1, wc = w & 1;
  f32x4 acc[4][4];
#pragma unroll
  for (int mi = 0; mi < 4; ++mi)
#pragma unroll
    for (int ni = 0; ni < 4; ++ni)
#pragma unroll
      for (int j = 0; j < 4; ++j) acc[mi][ni][j] = 0.f;

  for (int ks = 0; ks < 4; ++ks) {
    const int* idxp = (ks < 2) ? eu : ev;
#pragma unroll
    for (int i = 0; i < 4; ++i) {
      const int row = w * 32 + i * 8 + (l >> 3);
      const int ch = (l & 7) ^ (row & 7);
      const int nidx = idxp[bm + row];
      gload16(xbf + (size_t)nidx * 256 + (ks & 1) * 128 + ch * 16,
              As + w * 4096 + i * 1024);
      gload16(w1x + (size_t)row * 512 + ks * 128 + ch * 16,
              Bs + w * 4096 + i * 1024);
    }
    __syncthreads();
#pragma unroll
    for (int k0 = 0; k0 < 2; ++k0) {
      bf16x8 af[4], bff[4];
#pragma unroll
      for (int mi = 0; mi < 4; ++mi) {
        const int r = wr * 64 + mi * 16 + (l & 15);
        const int off = (k0 * 64 + (l >> 4) * 16) ^ ((r & 7) << 4);
        af[mi] = *(const bf16x8*)(As + r * 128 + off);
      }
#pragma unroll
      for (int ni = 0; ni < 4; ++ni) {
        const int r = wc * 64 + ni * 16 + (l & 15);
        const int off = (k0 * 64 + (l >> 4) * 16) ^ ((r & 7) << 4);
        bff[ni] = *(const bf16x8*)(Bs + r * 128 + off);
      }
#pragma unroll
      for (int mi = 0; mi < 4; ++mi)
#pragma unroll
        for (int ni = 0; ni < 4; ++ni)
          acc[mi][ni] = __builtin_amdgcn_mfma_f32_16x16x32_bf16(
              af[mi], bff[ni], acc[mi][ni], 0, 0, 0);
    }
    __syncthreads();
  }
  float w1c0[4], w1c1[4], bb[4];
#pragma unroll
  for (int ni = 0; ni < 4; ++ni) {
    const int col = wc * 64 + ni * 16 + (l & 15);
    w1c0[ni] = w1f[col * 258 + 256];
    w1c1[ni] = w1f[col * 258 + 257];
    bb[ni] = b1[col];
  }
#pragma unroll
  for (int mi = 0; mi < 4; ++mi)
#pragma unroll
    for (int j = 0; j < 4; ++j) {
      const int rl = wr * 64 + mi * 16 + (l >> 4) * 4 + j;
      const float2 e2 = *(const float2*)(ef + 2 * (size_t)(bm + rl));
#pragma unroll
      for (int ni = 0; ni < 4; ++ni) {
        float v = acc[mi][ni][j] + e2.x * w1c0[ni] + e2.y * w1c1[ni] + bb[ni];
        v = fmaxf(v, 0.f);
        const int col = wc * 64 + ni * 16 + (l & 15);
        const int off = (col * 2) ^ ((rl & 7) << 4);
        *(unsigned short*)(H1 + rl * 256 + off) = f2bf(v);
      }
    }
  __syncthreads();
  f32x4 acc2[4][4];
#pragma unroll
  for (int mi = 0; mi < 4; ++mi)
#pragma unroll
    for (int ni = 0; ni < 4; ++ni)
#pragma unroll
      for (int j = 0; j < 4; ++j) acc2[mi][ni][j] = 0.f;
  for (int ks2 = 0; ks2 < 2; ++ks2) {
#pragma unroll
    for (int i = 0; i < 4; ++i) {
      const int row = w * 32 + i * 8 + (l >> 3);
      const int ch = (l & 7) ^ (row & 7);
      gload16(w2 + (size_t)row * 256 + ks2 * 128 + ch * 16,
              Bs + w * 4096 + i * 1024);
    }
    __syncthreads();
#pragma unroll
    for (int k0 = 0; k0 < 2; ++k0) {
      bf16x8 af[4], bff[4];
#pragma unroll
      for (int mi = 0; mi < 4; ++mi) {
        const int r = wr * 64 + mi * 16 + (l & 15);
        const int off = (ks2 * 128 + k0 * 64 + (l >> 4) * 16) ^ ((r & 7) << 4);
        af[mi] = *(const bf16x8*)(H1 + r * 256 + off);
      }
#pragma unroll
      for (int ni = 0; ni < 4; ++ni) {
        const int r = wc * 64 + ni * 16 + (l & 15);
        const int off = (k0 * 64 + (l >> 4) * 16) ^ ((r & 7) << 4);
        bff[ni] = *(const bf16x8*)(Bs + r * 128 + off);
      }
#pragma unroll
      for (int mi = 0; mi < 4; ++mi)
#pragma unroll
        for (int ni = 0; ni < 4; ++ni)
          acc2[mi][ni] = __builtin_amdgcn_mfma_f32_16x16x32_bf16(
              af[mi], bff[ni], acc2[mi][ni], 0, 0, 0);
    }
    __syncthreads();
  }
  float b2v[4], w3v[4];
#pragma unroll
  for (int ni = 0; ni < 4; ++ni) {
    const int col = wc * 64 + ni * 16 + (l & 15);
    b2v[ni] = b2[col];
    w3v[ni] = w3[col];
  }
#pragma unroll
  for (int mi = 0; mi < 4; ++mi)
#pragma unroll
    for (int j = 0; j < 4; ++j) {
      const int rl = wr * 64 + mi * 16 + (l >> 4) * 4 + j;
      float p = 0.f;
#pragma unroll
      for (int ni = 0; ni < 4; ++ni) {
        const float h2 = fmaxf(acc2[mi][ni][j] + b2v[ni], 0.f);
        p = fmaf(h2, w3v[ni], p);
      }
      p += __shfl_xor(p, 1);
      p += __shfl_xor(p, 2);
      p += __shfl_xor(p, 4);
      p += __shfl_xor(p, 8);
      if ((l & 15) == 0) s_part[wc * 128 + rl] = p;
    }
  __syncthreads();
  if (t < 128) out[bm + t] = s_part[t] + s_part[128 + t] + b3[0];
}

// ---------------------------------------------------------------------------
extern "C" void kernel_launch(void* const* d_in, const int* in_sizes, int n_in,
                              void* d_out, int out_size, void* d_ws, size_t ws_size,
                              hipStream_t stream) {
  (void)in_sizes; (void)n_in; (void)out_size; (void)ws_size;
  const int*   type_idx   = (const int*)d_in[0];
  const int*   cat_idx    = (const int*)d_in[1];
  const float* log_degree = (const float*)d_in[2];
  const int*   ctx        = (const int*)d_in[3];
  const unsigned char* mask = (const unsigned char*)d_in[4];
  const int*   eu         = (const int*)d_in[5];
  const int*   ev         = (const int*)d_in[6];
  const float* ef         = (const float*)d_in[7];
  const float* type_embed = (const float*)d_in[8];
  const float* cat0       = (const float*)d_in[9];
  const float* cat1       = (const float*)d_in[10];
  const float* dw         = (const float*)d_in[11];
  const float* db         = (const float*)d_in[12];
  const float* proj_w     = (const float*)d_in[13];
  const float* proj_b     = (const float*)d_in[14];
  const float* qkv_w      = (const float*)d_in[15];
  const float* qkv_b      = (const float*)d_in[16];
  const float* out_w      = (const float*)d_in[17];
  const float* out_b      = (const float*)d_in[18];
  const float* w1         = (const float*)d_in[19];
  const float* b1         = (const float*)d_in[20];
  const float* w2         = (const float*)d_in[21];
  const float* b2         = (const float*)d_in[22];
  const float* w3         = (const float*)d_in[23];
  const float* b3         = (const float*)d_in[24];

  char* ws = (char*)d_ws;
  char* xbf     = ws;                       // [N][128] bf16   8 MB
  char* qkvbf   = ws + 8388608;             // [3][N][128] bf16 24 MB (planar)
  char* obf     = ws + 33554432;            // [N][128] bf16   8 MB
  char* featbf  = ws + 41943040;            // [N][192] bf16   12 MB
  char* qkvwbf  = ws + 54525952;            // 3*384*128 bf16
  char* outwbf  = ws + 54820864;            // 3*128*128 bf16
  char* projwbf = ws + 54919168;            // 128*192 bf16
  char* w1xbf   = ws + 54968320;            // 128*256 bf16
  char* w2bf    = ws + 55033856;            // 128*128 bf16
  int*  lengths = (int*)(ws + 55066624);
  int*  flag    = (int*)(ws + 55197696);

  hipMemsetAsync(flag, 0, sizeof(int), stream);
  detect_mask_kernel<<<256, 256, 0, stream>>>((const unsigned int*)mask, flag);
  lengths_kernel<<<NN / 256, 256, 0, stream>>>(mask, flag, lengths);

  prep_weights<<<1056, 256, 0, stream>>>(
      qkv_w, out_w, proj_w, w1, w2,
      (unsigned short*)qkvwbf, (unsigned short*)outwbf,
      (unsigned short*)projwbf, (unsigned short*)w1xbf, (unsigned short*)w2bf);
  feat_build<<<NN * 192 / 256, 256, 0, stream>>>(
      type_idx, cat_idx, log_degree, type_embed, cat0, cat1, dw, db,
      (unsigned short*)featbf);

  // encode: x = feat[192] @ projw^T + proj_b (no relu)
  mfma_gemm<<<dim3(NN / 128, 1), 256, 0, stream>>>(
      featbf, 384, projwbf, 384, proj_b, 3, 0, (unsigned short*)xbf, 128, 0);

  const size_t seg = (size_t)NN * 128;  // planar Q/K/V segment (elements)
  unsigned short* Qp = (unsigned short*)qkvbf;
  unsigned short* Kp = Qp + seg;
  unsigned short* Vp = Kp + seg;
  for (int layer = 0; layer < 3; ++layer) {
    mfma_gemm<<<dim3(NN / 128, 3), 256, 0, stream>>>(
        xbf, 256, qkvwbf + (size_t)layer * 98304, 256,
        qkv_b + (size_t)layer * 384, 2, 0, Qp, 128, seg);
    attn_kernel<<<NN / 4, 256, 0, stream>>>(
        Qp, Kp, Vp, ctx, lengths, (unsigned short*)obf);
    mfma_gemm<<<dim3(NN / 128, 1), 256, 0, stream>>>(
        obf, 256, outwbf + (size_t)layer * 32768, 256,
        out_b + (size_t)layer * 128, 2, 1, (unsigned short*)xbf, 128, 0);
  }

  edge_fused<<<EE / 128, 256, 0, stream>>>(
      xbf, eu, ev, ef, w1xbf, w1, b1, w2bf, b2, w3, b3, (float*)d_out);
}

// Round 9
// 240.966 us; speedup vs baseline: 1.1198x; 1.0248x over previous
//
#include <hip/hip_runtime.h>
#include <hip/hip_bf16.h>
#include <math.h>

#define NN 32768
#define LL 33
#define DD 128
#define EE 131072

typedef short bf16x8 __attribute__((ext_vector_type(8)));
typedef float f32x4 __attribute__((ext_vector_type(4)));

__device__ inline unsigned short f2bf(float f) {
  __hip_bfloat16 h = __float2bfloat16(f);
  return *reinterpret_cast<unsigned short*>(&h);
}
__device__ inline float bf2f(unsigned short u) {
  return __uint_as_float(((unsigned int)u) << 16);
}
// async global->LDS, 16B per lane. LDS dest is wave-uniform base + lane*16;
// global src is per-lane (we pre-swizzle the SOURCE so LDS stays linear).
__device__ inline void gload16(const void* g, void* lds) {
  __builtin_amdgcn_global_load_lds(
      (const __attribute__((address_space(1))) unsigned int*)g,
      (__attribute__((address_space(3))) unsigned int*)lds, 16, 0, 0);
}

// ---------------------------------------------------------------------------
// Parallel mask-layout detect (dword scan; see round-4 notes).
// ---------------------------------------------------------------------------
__global__ __launch_bounds__(256) void detect_mask_kernel(
    const unsigned int* __restrict__ mw, int* __restrict__ flag) {
  const int nd = NN * LL / 4;
  int found = 0;
  for (int p = blockIdx.x * 256 + threadIdx.x; p < nd; p += gridDim.x * 256) {
    if (mw[p] & 0xFFFFFF00u) found = 1;
  }
  __shared__ int s;
  if (threadIdx.x == 0) s = 0;
  __syncthreads();
  if (found) atomicOr(&s, 1);
  __syncthreads();
  if (threadIdx.x == 0 && s) atomicOr(flag, 1);
}

__global__ __launch_bounds__(256) void lengths_kernel(
    const unsigned char* __restrict__ mb, const int* __restrict__ flag,
    int* __restrict__ lengths) {
  const int i = blockIdx.x * 256 + threadIdx.x;
  if (i >= NN) return;
  const int esz = (*flag) ? 1 : 4;
  int len = LL;
  for (int j = 1; j < LL; ++j) {
    if (mb[(size_t)(i * LL + j) * esz] != 0) { len = j; break; }
  }
  lengths[i] = len;
}

// ---------------------------------------------------------------------------
// prep: fp32 weights -> bf16 copies (with K-padding where needed)
// ---------------------------------------------------------------------------
__global__ __launch_bounds__(256) void prep_weights(
    const float* __restrict__ qkvw, const float* __restrict__ outw,
    const float* __restrict__ projw, const float* __restrict__ w1,
    const float* __restrict__ w2,
    unsigned short* __restrict__ qkvwbf, unsigned short* __restrict__ outwbf,
    unsigned short* __restrict__ projwbf, unsigned short* __restrict__ w1xbf,
    unsigned short* __restrict__ w2bf) {
  int i = blockIdx.x * 256 + threadIdx.x;
  const int n_qkv = 3 * 384 * 128, n_out = 3 * 128 * 128;
  const int n_proj = 128 * 192, n_w1 = 128 * 256, n_w2 = 128 * 128;
  if (i < n_qkv) { qkvwbf[i] = f2bf(qkvw[i]); return; }
  i -= n_qkv;
  if (i < n_out) { outwbf[i] = f2bf(outw[i]); return; }
  i -= n_out;
  if (i < n_proj) {
    int n = i / 192, c = i - n * 192;
    projwbf[i] = f2bf(c < 160 ? projw[n * 160 + c] : 0.f);
    return;
  }
  i -= n_proj;
  if (i < n_w1) {
    int n = i / 256, c = i - n * 256;
    w1xbf[i] = f2bf(w1[n * 258 + c]);
    return;
  }
  i -= n_w1;
  if (i < n_w2) w2bf[i] = f2bf(w2[i]);
}

// ---------------------------------------------------------------------------
// feat_build: bf16 feature matrix [NN][192]
// ---------------------------------------------------------------------------
__global__ __launch_bounds__(256) void feat_build(
    const int* __restrict__ ti, const int* __restrict__ ci,
    const float* __restrict__ ldg, const float* __restrict__ temb,
    const float* __restrict__ c0, const float* __restrict__ c1,
    const float* __restrict__ dw, const float* __restrict__ db,
    unsigned short* __restrict__ feat) {
  const int i = blockIdx.x * 256 + threadIdx.x;
  if (i >= NN * 192) return;
  const int n = i / 192, c = i - n * 192;
  float v;
  if (c < 64)       v = temb[(size_t)ti[n] * 64 + c];
  else if (c < 96)  v = c0[(size_t)ci[2 * n] * 32 + (c - 64)];
  else if (c < 128) v = c1[(size_t)ci[2 * n + 1] * 32 + (c - 96)];
  else if (c < 160) v = fmaxf(fmaf(ldg[n], dw[c - 128], db[c - 128]), 0.f);
  else              v = 0.f;
  feat[i] = f2bf(v);
}

// ---------------------------------------------------------------------------
// bf16 MFMA GEMM: C[M,NO] = act(A @ W^T + bias), 128x128 tile, BK=64.
// (used only for the final out-proj -> xbf)
// ---------------------------------------------------------------------------
__global__ __launch_bounds__(256) void mfma_gemm(
    const char* __restrict__ A, int a_rs, const char* __restrict__ W, int w_rs,
    const float* __restrict__ bias, int nsteps, int relu,
    unsigned short* __restrict__ C, int c_rs, size_t seg) {
  __shared__ char As[16384];
  __shared__ char Bs[16384];
  const int t = threadIdx.x, l = t & 63, w = t >> 6;
  const int bm = blockIdx.x * 128, bn = blockIdx.y * 128;
  const int wr = w >> 1, wc = w & 1;
  f32x4 acc[4][4];
#pragma unroll
  for (int mi = 0; mi < 4; ++mi)
#pragma unroll
    for (int ni = 0; ni < 4; ++ni)
#pragma unroll
      for (int j = 0; j < 4; ++j) acc[mi][ni][j] = 0.f;

  for (int ks = 0; ks < nsteps; ++ks) {
#pragma unroll
    for (int i = 0; i < 4; ++i) {
      const int row = w * 32 + i * 8 + (l >> 3);
      const int ch = (l & 7) ^ (row & 7);
      gload16(A + (size_t)(bm + row) * a_rs + ks * 128 + ch * 16,
              As + w * 4096 + i * 1024);
      gload16(W + (size_t)(bn + row) * w_rs + ks * 128 + ch * 16,
              Bs + w * 4096 + i * 1024);
    }
    __syncthreads();
#pragma unroll
    for (int k0 = 0; k0 < 2; ++k0) {
      bf16x8 af[4], bff[4];
#pragma unroll
      for (int mi = 0; mi < 4; ++mi) {
        const int r = wr * 64 + mi * 16 + (l & 15);
        const int off = (k0 * 64 + (l >> 4) * 16) ^ ((r & 7) << 4);
        af[mi] = *(const bf16x8*)(As + r * 128 + off);
      }
#pragma unroll
      for (int ni = 0; ni < 4; ++ni) {
        const int r = wc * 64 + ni * 16 + (l & 15);
        const int off = (k0 * 64 + (l >> 4) * 16) ^ ((r & 7) << 4);
        bff[ni] = *(const bf16x8*)(Bs + r * 128 + off);
      }
#pragma unroll
      for (int mi = 0; mi < 4; ++mi)
#pragma unroll
        for (int ni = 0; ni < 4; ++ni)
          acc[mi][ni] = __builtin_amdgcn_mfma_f32_16x16x32_bf16(
              af[mi], bff[ni], acc[mi][ni], 0, 0, 0);
    }
    __syncthreads();
  }
  unsigned short* Cw = C;
  int coloff = bn;
  if (seg) { Cw = C + (size_t)blockIdx.y * seg; coloff = 0; }
#pragma unroll
  for (int ni = 0; ni < 4; ++ni) {
    const int lc = wc * 64 + ni * 16 + (l & 15);
    const float bz = bias[bn + lc];
    const int col = coloff + lc;
#pragma unroll
    for (int mi = 0; mi < 4; ++mi)
#pragma unroll
      for (int j = 0; j < 4; ++j) {
        const int row = bm + wr * 64 + mi * 16 + (l >> 4) * 4 + j;
        float v = acc[mi][ni][j] + bz;
        if (relu) v = fmaxf(v, 0.f);
        Cw[(size_t)row * c_rs + col] = f2bf(v);
      }
  }
}

// ---------------------------------------------------------------------------
// Dual GEMM: X = act1(A @ W1^T + b1)  [128 cols, kept in LDS],
// then for ny in 0..NY-1: OUT_ny = X @ W2_ny^T + b2_ny -> C + ny*seg.
// Fuses out-proj(l)+QKV(l+1) (and proj+QKV0), eliminating the x round-trip.
// W2 rows are 256 B (K=128). LDS: As 16K | Bs 16K | H 32K (X, swizzled).
// ---------------------------------------------------------------------------
__global__ __launch_bounds__(256) void dual_gemm(
    const char* __restrict__ A, int a_rs, const char* __restrict__ W1,
    int w1_rs, const float* __restrict__ b1, int nsteps1, int relu1,
    const char* __restrict__ W2, const float* __restrict__ b2, int NY,
    unsigned short* __restrict__ C, int c_rs, size_t seg) {
  __shared__ char lds[65536];
  char* As = lds;
  char* Bs = lds + 16384;
  char* H  = lds + 32768;
  const int t = threadIdx.x, l = t & 63, w = t >> 6;
  const int bm = blockIdx.x * 128;
  const int wr = w >> 1, wc = w & 1;
  f32x4 acc[4][4];
#pragma unroll
  for (int mi = 0; mi < 4; ++mi)
#pragma unroll
    for (int ni = 0; ni < 4; ++ni)
#pragma unroll
      for (int j = 0; j < 4; ++j) acc[mi][ni][j] = 0.f;

  // phase A: X = act1(A @ W1^T + b1)
  for (int ks = 0; ks < nsteps1; ++ks) {
#pragma unroll
    for (int i = 0; i < 4; ++i) {
      const int row = w * 32 + i * 8 + (l >> 3);
      const int ch = (l & 7) ^ (row & 7);
      gload16(A + (size_t)(bm + row) * a_rs + ks * 128 + ch * 16,
              As + w * 4096 + i * 1024);
      gload16(W1 + (size_t)row * w1_rs + ks * 128 + ch * 16,
              Bs + w * 4096 + i * 1024);
    }
    __syncthreads();
#pragma unroll
    for (int k0 = 0; k0 < 2; ++k0) {
      bf16x8 af[4], bff[4];
#pragma unroll
      for (int mi = 0; mi < 4; ++mi) {
        const int r = wr * 64 + mi * 16 + (l & 15);
        const int off = (k0 * 64 + (l >> 4) * 16) ^ ((r & 7) << 4);
        af[mi] = *(const bf16x8*)(As + r * 128 + off);
      }
#pragma unroll
      for (int ni = 0; ni < 4; ++ni) {
        const int r = wc * 64 + ni * 16 + (l & 15);
        const int off = (k0 * 64 + (l >> 4) * 16) ^ ((r & 7) << 4);
        bff[ni] = *(const bf16x8*)(Bs + r * 128 + off);
      }
#pragma unroll
      for (int mi = 0; mi < 4; ++mi)
#pragma unroll
        for (int ni = 0; ni < 4; ++ni)
          acc[mi][ni] = __builtin_amdgcn_mfma_f32_16x16x32_bf16(
              af[mi], bff[ni], acc[mi][ni], 0, 0, 0);
    }
    __syncthreads();
  }
  // X -> H (bf16, swizzled rows of 256 B)
#pragma unroll
  for (int mi = 0; mi < 4; ++mi)
#pragma unroll
    for (int j = 0; j < 4; ++j) {
      const int rl = wr * 64 + mi * 16 + (l >> 4) * 4 + j;
#pragma unroll
      for (int ni = 0; ni < 4; ++ni) {
        const int col = wc * 64 + ni * 16 + (l & 15);
        float v = acc[mi][ni][j] + b1[col];
        if (relu1) v = fmaxf(v, 0.f);
        const int off = (col * 2) ^ ((rl & 7) << 4);
        *(unsigned short*)(H + rl * 256 + off) = f2bf(v);
      }
    }
  // phase B: OUT_ny = X @ W2_ny^T + b2_ny
  for (int ny = 0; ny < NY; ++ny) {
    f32x4 acc2[4][4];
#pragma unroll
    for (int mi = 0; mi < 4; ++mi)
#pragma unroll
      for (int ni = 0; ni < 4; ++ni)
#pragma unroll
        for (int j = 0; j < 4; ++j) acc2[mi][ni][j] = 0.f;
    for (int ks = 0; ks < 2; ++ks) {
#pragma unroll
      for (int i = 0; i < 4; ++i) {
        const int row = w * 32 + i * 8 + (l >> 3);
        const int ch = (l & 7) ^ (row & 7);
        gload16(W2 + (size_t)(ny * 128 + row) * 256 + ks * 128 + ch * 16,
                Bs + w * 4096 + i * 1024);
      }
      __syncthreads();   // also guarantees H writes are visible (ny=0,ks=0)
#pragma unroll
      for (int k0 = 0; k0 < 2; ++k0) {
        bf16x8 af[4], bff[4];
#pragma unroll
        for (int mi = 0; mi < 4; ++mi) {
          const int r = wr * 64 + mi * 16 + (l & 15);
          const int off = (ks * 128 + k0 * 64 + (l >> 4) * 16) ^ ((r & 7) << 4);
          af[mi] = *(const bf16x8*)(H + r * 256 + off);
        }
#pragma unroll
        for (int ni = 0; ni < 4; ++ni) {
          const int r = wc * 64 + ni * 16 + (l & 15);
          const int off = (k0 * 64 + (l >> 4) * 16) ^ ((r & 7) << 4);
          bff[ni] = *(const bf16x8*)(Bs + r * 128 + off);
        }
#pragma unroll
        for (int mi = 0; mi < 4; ++mi)
#pragma unroll
          for (int ni = 0; ni < 4; ++ni)
            acc2[mi][ni] = __builtin_amdgcn_mfma_f32_16x16x32_bf16(
                af[mi], bff[ni], acc2[mi][ni], 0, 0, 0);
      }
      __syncthreads();
    }
    unsigned short* Cw = C + (size_t)ny * seg;
#pragma unroll
    for (int ni = 0; ni < 4; ++ni) {
      const int lc = wc * 64 + ni * 16 + (l & 15);
      const float bz = b2[ny * 128 + lc];
#pragma unroll
      for (int mi = 0; mi < 4; ++mi)
#pragma unroll
        for (int j = 0; j < 4; ++j) {
          const int row = bm + wr * 64 + mi * 16 + (l >> 4) * 4 + j;
          Cw[(size_t)row * c_rs + lc] = f2bf(acc2[mi][ni][j] + bz);
        }
    }
  }
}

// ---------------------------------------------------------------------------
// Attention, planar Q/K/V [N][128] bf16. Quad-parallel, 8 neighbors/iter:
// each quad q4 handles positions l0+q4 and l0+q4+4 (16 loads in flight).
// Softmax unshifted (exact; scores O(1)). Quad partials via xor-16/32.
// ---------------------------------------------------------------------------
__global__ __launch_bounds__(256) void attn_kernel(
    const unsigned short* __restrict__ Q, const unsigned short* __restrict__ K,
    const unsigned short* __restrict__ V, const int* __restrict__ ctx,
    const int* __restrict__ lengths, unsigned short* __restrict__ O) {
  const int t = threadIdx.x, w = t >> 6, lane = t & 63;
  const int node = blockIdx.x * 4 + w;
  const int q4 = lane >> 4, s = lane & 15;
  const int len = lengths[node];
  const int idxv = ctx[(size_t)node * LL + (lane < LL ? lane : 0)];
  const bf16x8 qv = *(const bf16x8*)(Q + (size_t)node * 128 + s * 8);
  float qf[8];
#pragma unroll
  for (int j = 0; j < 8; ++j)
    qf[j] = bf2f((unsigned short)qv[j]) * 0.17677669529663687f;  // /sqrt(32)
  float av[8];
#pragma unroll
  for (int j = 0; j < 8; ++j) av[j] = 0.f;
  float ssum = 0.f;

  int ok0 = q4 < len, ok1 = q4 + 4 < len;
  int ki0 = __shfl(idxv, ok0 ? q4 : 0);
  int ki1 = __shfl(idxv, ok1 ? q4 + 4 : 0);
  bf16x8 kv0 = *(const bf16x8*)(K + (size_t)ki0 * 128 + s * 8);
  bf16x8 vv0 = *(const bf16x8*)(V + (size_t)ki0 * 128 + s * 8);
  bf16x8 kv1 = *(const bf16x8*)(K + (size_t)ki1 * 128 + s * 8);
  bf16x8 vv1 = *(const bf16x8*)(V + (size_t)ki1 * 128 + s * 8);

  for (int l0 = 0; l0 < len; l0 += 8) {
    const int n0 = l0 + 8 + q4, n1 = l0 + 12 + q4;
    const int okn0 = n0 < len, okn1 = n1 < len;
    const int kin0 = __shfl(idxv, okn0 ? n0 : 0);
    const int kin1 = __shfl(idxv, okn1 ? n1 : 0);
    bf16x8 kvn0 = kv0, vvn0 = vv0, kvn1 = kv1, vvn1 = vv1;
    if (l0 + 8 < len) {
      kvn0 = *(const bf16x8*)(K + (size_t)kin0 * 128 + s * 8);
      vvn0 = *(const bf16x8*)(V + (size_t)kin0 * 128 + s * 8);
      kvn1 = *(const bf16x8*)(K + (size_t)kin1 * 128 + s * 8);
      vvn1 = *(const bf16x8*)(V + (size_t)kin1 * 128 + s * 8);
    }
    float sc0 = 0.f, sc1 = 0.f;
#pragma unroll
    for (int j = 0; j < 8; ++j) {
      sc0 = fmaf(qf[j], bf2f((unsigned short)kv0[j]), sc0);
      sc1 = fmaf(qf[j], bf2f((unsigned short)kv1[j]), sc1);
    }
    sc0 += __shfl_xor(sc0, 1);
    sc0 += __shfl_xor(sc0, 2);
    sc1 += __shfl_xor(sc1, 1);
    sc1 += __shfl_xor(sc1, 2);
    const float e0 = ok0 ? __expf(sc0) : 0.f;
    const float e1 = ok1 ? __expf(sc1) : 0.f;
    ssum += e0 + e1;
#pragma unroll
    for (int j = 0; j < 8; ++j) {
      av[j] = fmaf(e0, bf2f((unsigned short)vv0[j]), av[j]);
      av[j] = fmaf(e1, bf2f((unsigned short)vv1[j]), av[j]);
    }
    kv0 = kvn0; vv0 = vvn0; kv1 = kvn1; vv1 = vvn1;
    ok0 = okn0; ok1 = okn1;
  }
  // combine the 4 quads (lane bits 4,5)
#pragma unroll
  for (int j = 0; j < 8; ++j) {
    av[j] += __shfl_xor(av[j], 16);
    av[j] += __shfl_xor(av[j], 32);
  }
  ssum += __shfl_xor(ssum, 16);
  ssum += __shfl_xor(ssum, 32);
  if (q4 == 0) {
    const float inv = 1.f / ssum;
    unsigned int o[4];
#pragma unroll
    for (int p = 0; p < 4; ++p)
      o[p] = (unsigned int)f2bf(av[2 * p] * inv) |
             ((unsigned int)f2bf(av[2 * p + 1] * inv) << 16);
    *(uint4*)(O + (size_t)node * DD + s * 8) =
        make_uint4(o[0], o[1], o[2], o[3]);
  }
}

// ---------------------------------------------------------------------------
// Fused edge MLP, 128 edges/block, all-MFMA (unchanged).
// ---------------------------------------------------------------------------
__global__ __launch_bounds__(256) void edge_fused(
    const char* __restrict__ xbf, const int* __restrict__ eu,
    const int* __restrict__ ev, const float* __restrict__ ef,
    const char* __restrict__ w1x, const float* __restrict__ w1f,
    const float* __restrict__ b1, const char* __restrict__ w2,
    const float* __restrict__ b2, const float* __restrict__ w3,
    const float* __restrict__ b3, float* __restrict__ out) {
  __shared__ char lds[65536];
  char* As = lds;
  char* Bs = lds + 16384;
  char* H1 = lds + 32768;
  float* s_part = (float*)lds;
  const int t = threadIdx.x, l = t & 63, w = t >> 6;
  const int bm = blockIdx.x * 128;
  const int wr = w >> 1, wc = w & 1;
  f32x4 acc[4][4];
#pragma unroll
  for (int mi = 0; mi < 4; ++mi)
#pragma unroll
    for (int ni = 0; ni < 4; ++ni)
#pragma unroll
      for (int j = 0; j < 4; ++j) acc[mi][ni][j] = 0.f;

  for (int ks = 0; ks < 4; ++ks) {
    const int* idxp = (ks < 2) ? eu : ev;
#pragma unroll
    for (int i = 0; i < 4; ++i) {
      const int row = w * 32 + i * 8 + (l >> 3);
      const int ch = (l & 7) ^ (row & 7);
      const int nidx = idxp[bm + row];
      gload16(xbf + (size_t)nidx * 256 + (ks & 1) * 128 + ch * 16,
              As + w * 4096 + i * 1024);
      gload16(w1x + (size_t)row * 512 + ks * 128 + ch * 16,
              Bs + w * 4096 + i * 1024);
    }
    __syncthreads();
#pragma unroll
    for (int k0 = 0; k0 < 2; ++k0) {
      bf16x8 af[4], bff[4];
#pragma unroll
      for (int mi = 0; mi < 4; ++mi) {
        const int r = wr * 64 + mi * 16 + (l & 15);
        const int off = (k0 * 64 + (l >> 4) * 16) ^ ((r & 7) << 4);
        af[mi] = *(const bf16x8*)(As + r * 128 + off);
      }
#pragma unroll
      for (int ni = 0; ni < 4; ++ni) {
        const int r = wc * 64 + ni * 16 + (l & 15);
        const int off = (k0 * 64 + (l >> 4) * 16) ^ ((r & 7) << 4);
        bff[ni] = *(const bf16x8*)(Bs + r * 128 + off);
      }
#pragma unroll
      for (int mi = 0; mi < 4; ++mi)
#pragma unroll
        for (int ni = 0; ni < 4; ++ni)
          acc[mi][ni] = __builtin_amdgcn_mfma_f32_16x16x32_bf16(
              af[mi], bff[ni], acc[mi][ni], 0, 0, 0);
    }
    __syncthreads();
  }
  float w1c0[4], w1c1[4], bb[4];
#pragma unroll
  for (int ni = 0; ni < 4; ++ni) {
    const int col = wc * 64 + ni * 16 + (l & 15);
    w1c0[ni] = w1f[col * 258 + 256];
    w1c1[ni] = w1f[col * 258 + 257];
    bb[ni] = b1[col];
  }
#pragma unroll
  for (int mi = 0; mi < 4; ++mi)
#pragma unroll
    for (int j = 0; j < 4; ++j) {
      const int rl = wr * 64 + mi * 16 + (l >> 4) * 4 + j;
      const float2 e2 = *(const float2*)(ef + 2 * (size_t)(bm + rl));
#pragma unroll
      for (int ni = 0; ni < 4; ++ni) {
        float v = acc[mi][ni][j] + e2.x * w1c0[ni] + e2.y * w1c1[ni] + bb[ni];
        v = fmaxf(v, 0.f);
        const int col = wc * 64 + ni * 16 + (l & 15);
        const int off = (col * 2) ^ ((rl & 7) << 4);
        *(unsigned short*)(H1 + rl * 256 + off) = f2bf(v);
      }
    }
  __syncthreads();
  f32x4 acc2[4][4];
#pragma unroll
  for (int mi = 0; mi < 4; ++mi)
#pragma unroll
    for (int ni = 0; ni < 4; ++ni)
#pragma unroll
      for (int j = 0; j < 4; ++j) acc2[mi][ni][j] = 0.f;
  for (int ks2 = 0; ks2 < 2; ++ks2) {
#pragma unroll
    for (int i = 0; i < 4; ++i) {
      const int row = w * 32 + i * 8 + (l >> 3);
      const int ch = (l & 7) ^ (row & 7);
      gload16(w2 + (size_t)row * 256 + ks2 * 128 + ch * 16,
              Bs + w * 4096 + i * 1024);
    }
    __syncthreads();
#pragma unroll
    for (int k0 = 0; k0 < 2; ++k0) {
      bf16x8 af[4], bff[4];
#pragma unroll
      for (int mi = 0; mi < 4; ++mi) {
        const int r = wr * 64 + mi * 16 + (l & 15);
        const int off = (ks2 * 128 + k0 * 64 + (l >> 4) * 16) ^ ((r & 7) << 4);
        af[mi] = *(const bf16x8*)(H1 + r * 256 + off);
      }
#pragma unroll
      for (int ni = 0; ni < 4; ++ni) {
        const int r = wc * 64 + ni * 16 + (l & 15);
        const int off = (k0 * 64 + (l >> 4) * 16) ^ ((r & 7) << 4);
        bff[ni] = *(const bf16x8*)(Bs + r * 128 + off);
      }
#pragma unroll
      for (int mi = 0; mi < 4; ++mi)
#pragma unroll
        for (int ni = 0; ni < 4; ++ni)
          acc2[mi][ni] = __builtin_amdgcn_mfma_f32_16x16x32_bf16(
              af[mi], bff[ni], acc2[mi][ni], 0, 0, 0);
    }
    __syncthreads();
  }
  float b2v[4], w3v[4];
#pragma unroll
  for (int ni = 0; ni < 4; ++ni) {
    const int col = wc * 64 + ni * 16 + (l & 15);
    b2v[ni] = b2[col];
    w3v[ni] = w3[col];
  }
#pragma unroll
  for (int mi = 0; mi < 4; ++mi)
#pragma unroll
    for (int j = 0; j < 4; ++j) {
      const int rl = wr * 64 + mi * 16 + (l >> 4) * 4 + j;
      float p = 0.f;
#pragma unroll
      for (int ni = 0; ni < 4; ++ni) {
        const float h2 = fmaxf(acc2[mi][ni][j] + b2v[ni], 0.f);
        p = fmaf(h2, w3v[ni], p);
      }
      p += __shfl_xor(p, 1);
      p += __shfl_xor(p, 2);
      p += __shfl_xor(p, 4);
      p += __shfl_xor(p, 8);
      if ((l & 15) == 0) s_part[wc * 128 + rl] = p;
    }
  __syncthreads();
  if (t < 128) out[bm + t] = s_part[t] + s_part[128 + t] + b3[0];
}

// ---------------------------------------------------------------------------
extern "C" void kernel_launch(void* const* d_in, const int* in_sizes, int n_in,
                              void* d_out, int out_size, void* d_ws, size_t ws_size,
                              hipStream_t stream) {
  (void)in_sizes; (void)n_in; (void)out_size; (void)ws_size;
  const int*   type_idx   = (const int*)d_in[0];
  const int*   cat_idx    = (const int*)d_in[1];
  const float* log_degree = (const float*)d_in[2];
  const int*   ctx        = (const int*)d_in[3];
  const unsigned char* mask = (const unsigned char*)d_in[4];
  const int*   eu         = (const int*)d_in[5];
  const int*   ev         = (const int*)d_in[6];
  const float* ef         = (const float*)d_in[7];
  const float* type_embed = (const float*)d_in[8];
  const float* cat0       = (const float*)d_in[9];
  const float* cat1       = (const float*)d_in[10];
  const float* dw         = (const float*)d_in[11];
  const float* db         = (const float*)d_in[12];
  const float* proj_w     = (const float*)d_in[13];
  const float* proj_b     = (const float*)d_in[14];
  const float* qkv_w      = (const float*)d_in[15];
  const float* qkv_b      = (const float*)d_in[16];
  const float* out_w      = (const float*)d_in[17];
  const float* out_b      = (const float*)d_in[18];
  const float* w1         = (const float*)d_in[19];
  const float* b1         = (const float*)d_in[20];
  const float* w2         = (const float*)d_in[21];
  const float* b2         = (const float*)d_in[22];
  const float* w3         = (const float*)d_in[23];
  const float* b3         = (const float*)d_in[24];

  char* ws = (char*)d_ws;
  char* xbf     = ws;                       // [N][128] bf16   8 MB
  char* qkvbf   = ws + 8388608;             // [3][N][128] bf16 24 MB (planar)
  char* obf     = ws + 33554432;            // [N][128] bf16   8 MB
  char* featbf  = ws + 41943040;            // [N][192] bf16   12 MB
  char* qkvwbf  = ws + 54525952;            // 3*384*128 bf16
  char* outwbf  = ws + 54820864;            // 3*128*128 bf16
  char* projwbf = ws + 54919168;            // 128*192 bf16
  char* w1xbf   = ws + 54968320;            // 128*256 bf16
  char* w2bf    = ws + 55033856;            // 128*128 bf16
  int*  lengths = (int*)(ws + 55066624);
  int*  flag    = (int*)(ws + 55197696);

  hipMemsetAsync(flag, 0, sizeof(int), stream);
  detect_mask_kernel<<<256, 256, 0, stream>>>((const unsigned int*)mask, flag);
  lengths_kernel<<<NN / 256, 256, 0, stream>>>(mask, flag, lengths);

  prep_weights<<<1056, 256, 0, stream>>>(
      qkv_w, out_w, proj_w, w1, w2,
      (unsigned short*)qkvwbf, (unsigned short*)outwbf,
      (unsigned short*)projwbf, (unsigned short*)w1xbf, (unsigned short*)w2bf);
  feat_build<<<NN * 192 / 256, 256, 0, stream>>>(
      type_idx, cat_idx, log_degree, type_embed, cat0, cat1, dw, db,
      (unsigned short*)featbf);

  const size_t seg = (size_t)NN * 128;  // planar Q/K/V segment (elements)
  unsigned short* Qp = (unsigned short*)qkvbf;
  unsigned short* Kp = Qp + seg;
  unsigned short* Vp = Kp + seg;

  // encode fused: X = feat@projw^T + proj_b (no relu); QKV0 = X@Wqkv0^T + b
  dual_gemm<<<NN / 128, 256, 0, stream>>>(
      featbf, 384, projwbf, 384, proj_b, 3, 0,
      qkvwbf, qkv_b, 3, Qp, 128, seg);

  for (int layer = 0; layer < 3; ++layer) {
    attn_kernel<<<NN / 4, 256, 0, stream>>>(
        Qp, Kp, Vp, ctx, lengths, (unsigned short*)obf);
    if (layer < 2) {
      // fused: x = relu(O@Wout_l^T + b_l); QKV_{l+1} = x@Wqkv_{l+1}^T + b
      dual_gemm<<<NN / 128, 256, 0, stream>>>(
          obf, 256, outwbf + (size_t)layer * 32768, 256,
          out_b + (size_t)layer * 128, 2, 1,
          qkvwbf + (size_t)(layer + 1) * 98304,
          qkv_b + (size_t)(layer + 1) * 384, 3, Qp, 128, seg);
    } else {
      mfma_gemm<<<dim3(NN / 128, 1), 256, 0, stream>>>(
          obf, 256, outwbf + (size_t)layer * 32768, 256,
          out_b + (size_t)layer * 128, 2, 1, (unsigned short*)xbf, 128, 0);
    }
  }

  edge_fused<<<EE / 128, 256, 0, stream>>>(
      xbf, eu, ev, ef, w1xbf, w1, b1, w2bf, b2, w3, b3, (float*)d_out);
}

// Round 10
// 240.801 us; speedup vs baseline: 1.1206x; 1.0007x over previous
//
#include <hip/hip_runtime.h>
#include <hip/hip_bf16.h>
#include <math.h>

#define NN 32768
#define LL 33
#define DD 128
#define EE 131072

typedef short bf16x8 __attribute__((ext_vector_type(8)));
typedef float f32x4 __attribute__((ext_vector_type(4)));
typedef __bf16 bf2_t __attribute__((ext_vector_type(2)));

#if defined(__has_builtin)
#if __has_builtin(__builtin_amdgcn_fdot2_f32_bf16)
#define USE_DOT2 1
#endif
#endif

__device__ inline unsigned short f2bf(float f) {
  __hip_bfloat16 h = __float2bfloat16(f);
  return *reinterpret_cast<unsigned short*>(&h);
}
__device__ inline float bf2f(unsigned short u) {
  return __uint_as_float(((unsigned int)u) << 16);
}
// async global->LDS, 16B per lane. LDS dest is wave-uniform base + lane*16;
// global src is per-lane (we pre-swizzle the SOURCE so LDS stays linear).
__device__ inline void gload16(const void* g, void* lds) {
  __builtin_amdgcn_global_load_lds(
      (const __attribute__((address_space(1))) unsigned int*)g,
      (__attribute__((address_space(3))) unsigned int*)lds, 16, 0, 0);
}

// ---------------------------------------------------------------------------
// Parallel mask-layout detect (dword scan; see round-4 notes).
// ---------------------------------------------------------------------------
__global__ __launch_bounds__(256) void detect_mask_kernel(
    const unsigned int* __restrict__ mw, int* __restrict__ flag) {
  const int nd = NN * LL / 4;
  int found = 0;
  for (int p = blockIdx.x * 256 + threadIdx.x; p < nd; p += gridDim.x * 256) {
    if (mw[p] & 0xFFFFFF00u) found = 1;
  }
  __shared__ int s;
  if (threadIdx.x == 0) s = 0;
  __syncthreads();
  if (found) atomicOr(&s, 1);
  __syncthreads();
  if (threadIdx.x == 0 && s) atomicOr(flag, 1);
}

__global__ __launch_bounds__(256) void lengths_kernel(
    const unsigned char* __restrict__ mb, const int* __restrict__ flag,
    int* __restrict__ lengths) {
  const int i = blockIdx.x * 256 + threadIdx.x;
  if (i >= NN) return;
  const int esz = (*flag) ? 1 : 4;
  int len = LL;
  for (int j = 1; j < LL; ++j) {
    if (mb[(size_t)(i * LL + j) * esz] != 0) { len = j; break; }
  }
  lengths[i] = len;
}

// ---------------------------------------------------------------------------
// prep_all: feat_build (bf16 [NN][192]) + weight bf16 conversions, one kernel.
// ---------------------------------------------------------------------------
#define NFEAT (NN * 192)
__global__ __launch_bounds__(256) void prep_all(
    const int* __restrict__ ti, const int* __restrict__ ci,
    const float* __restrict__ ldg, const float* __restrict__ temb,
    const float* __restrict__ c0, const float* __restrict__ c1,
    const float* __restrict__ dw, const float* __restrict__ db,
    unsigned short* __restrict__ feat,
    const float* __restrict__ qkvw, const float* __restrict__ outw,
    const float* __restrict__ projw, const float* __restrict__ w1,
    const float* __restrict__ w2,
    unsigned short* __restrict__ qkvwbf, unsigned short* __restrict__ outwbf,
    unsigned short* __restrict__ projwbf, unsigned short* __restrict__ w1xbf,
    unsigned short* __restrict__ w2bf) {
  int i = blockIdx.x * 256 + threadIdx.x;
  if (i < NFEAT) {
    const int n = i / 192, c = i - n * 192;
    float v;
    if (c < 64)       v = temb[(size_t)ti[n] * 64 + c];
    else if (c < 96)  v = c0[(size_t)ci[2 * n] * 32 + (c - 64)];
    else if (c < 128) v = c1[(size_t)ci[2 * n + 1] * 32 + (c - 96)];
    else if (c < 160) v = fmaxf(fmaf(ldg[n], dw[c - 128], db[c - 128]), 0.f);
    else              v = 0.f;
    feat[i] = f2bf(v);
    return;
  }
  i -= NFEAT;
  const int n_qkv = 3 * 384 * 128, n_out = 3 * 128 * 128;
  const int n_proj = 128 * 192, n_w1 = 128 * 256, n_w2 = 128 * 128;
  if (i < n_qkv) { qkvwbf[i] = f2bf(qkvw[i]); return; }
  i -= n_qkv;
  if (i < n_out) { outwbf[i] = f2bf(outw[i]); return; }
  i -= n_out;
  if (i < n_proj) {
    int n = i / 192, c = i - n * 192;
    projwbf[i] = f2bf(c < 160 ? projw[n * 160 + c] : 0.f);
    return;
  }
  i -= n_proj;
  if (i < n_w1) {
    int n = i / 256, c = i - n * 256;
    w1xbf[i] = f2bf(w1[n * 258 + c]);
    return;
  }
  i -= n_w1;
  if (i < n_w2) w2bf[i] = f2bf(w2[i]);
}
#define NPREP (NFEAT + 3 * 384 * 128 + 3 * 128 * 128 + 128 * 192 + 128 * 256 + 128 * 128)

// ---------------------------------------------------------------------------
// bf16 MFMA GEMM: C[M,NO] = act(A @ W^T + bias), 128x128 tile, BK=64.
// (used only for the final out-proj -> xbf)
// ---------------------------------------------------------------------------
__global__ __launch_bounds__(256) void mfma_gemm(
    const char* __restrict__ A, int a_rs, const char* __restrict__ W, int w_rs,
    const float* __restrict__ bias, int nsteps, int relu,
    unsigned short* __restrict__ C, int c_rs, size_t seg) {
  __shared__ char As[16384];
  __shared__ char Bs[16384];
  const int t = threadIdx.x, l = t & 63, w = t >> 6;
  const int bm = blockIdx.x * 128, bn = blockIdx.y * 128;
  const int wr = w >> 1, wc = w & 1;
  f32x4 acc[4][4];
#pragma unroll
  for (int mi = 0; mi < 4; ++mi)
#pragma unroll
    for (int ni = 0; ni < 4; ++ni)
#pragma unroll
      for (int j = 0; j < 4; ++j) acc[mi][ni][j] = 0.f;

  for (int ks = 0; ks < nsteps; ++ks) {
#pragma unroll
    for (int i = 0; i < 4; ++i) {
      const int row = w * 32 + i * 8 + (l >> 3);
      const int ch = (l & 7) ^ (row & 7);
      gload16(A + (size_t)(bm + row) * a_rs + ks * 128 + ch * 16,
              As + w * 4096 + i * 1024);
      gload16(W + (size_t)(bn + row) * w_rs + ks * 128 + ch * 16,
              Bs + w * 4096 + i * 1024);
    }
    __syncthreads();
#pragma unroll
    for (int k0 = 0; k0 < 2; ++k0) {
      bf16x8 af[4], bff[4];
#pragma unroll
      for (int mi = 0; mi < 4; ++mi) {
        const int r = wr * 64 + mi * 16 + (l & 15);
        const int off = (k0 * 64 + (l >> 4) * 16) ^ ((r & 7) << 4);
        af[mi] = *(const bf16x8*)(As + r * 128 + off);
      }
#pragma unroll
      for (int ni = 0; ni < 4; ++ni) {
        const int r = wc * 64 + ni * 16 + (l & 15);
        const int off = (k0 * 64 + (l >> 4) * 16) ^ ((r & 7) << 4);
        bff[ni] = *(const bf16x8*)(Bs + r * 128 + off);
      }
#pragma unroll
      for (int mi = 0; mi < 4; ++mi)
#pragma unroll
        for (int ni = 0; ni < 4; ++ni)
          acc[mi][ni] = __builtin_amdgcn_mfma_f32_16x16x32_bf16(
              af[mi], bff[ni], acc[mi][ni], 0, 0, 0);
    }
    __syncthreads();
  }
  unsigned short* Cw = C;
  int coloff = bn;
  if (seg) { Cw = C + (size_t)blockIdx.y * seg; coloff = 0; }
#pragma unroll
  for (int ni = 0; ni < 4; ++ni) {
    const int lc = wc * 64 + ni * 16 + (l & 15);
    const float bz = bias[bn + lc];
    const int col = coloff + lc;
#pragma unroll
    for (int mi = 0; mi < 4; ++mi)
#pragma unroll
      for (int j = 0; j < 4; ++j) {
        const int row = bm + wr * 64 + mi * 16 + (l >> 4) * 4 + j;
        float v = acc[mi][ni][j] + bz;
        if (relu) v = fmaxf(v, 0.f);
        Cw[(size_t)row * c_rs + col] = f2bf(v);
      }
  }
}

// ---------------------------------------------------------------------------
// Dual GEMM: X = act1(A @ W1^T + b1)  [128 cols, kept in LDS],
// then for ny in 0..NY-1: OUT_ny = X @ W2_ny^T + b2_ny -> C + ny*seg.
// ---------------------------------------------------------------------------
__global__ __launch_bounds__(256) void dual_gemm(
    const char* __restrict__ A, int a_rs, const char* __restrict__ W1,
    int w1_rs, const float* __restrict__ b1, int nsteps1, int relu1,
    const char* __restrict__ W2, const float* __restrict__ b2, int NY,
    unsigned short* __restrict__ C, int c_rs, size_t seg) {
  __shared__ char lds[65536];
  char* As = lds;
  char* Bs = lds + 16384;
  char* H  = lds + 32768;
  const int t = threadIdx.x, l = t & 63, w = t >> 6;
  const int bm = blockIdx.x * 128;
  const int wr = w >> 1, wc = w & 1;
  f32x4 acc[4][4];
#pragma unroll
  for (int mi = 0; mi < 4; ++mi)
#pragma unroll
    for (int ni = 0; ni < 4; ++ni)
#pragma unroll
      for (int j = 0; j < 4; ++j) acc[mi][ni][j] = 0.f;

  // phase A: X = act1(A @ W1^T + b1)
  for (int ks = 0; ks < nsteps1; ++ks) {
#pragma unroll
    for (int i = 0; i < 4; ++i) {
      const int row = w * 32 + i * 8 + (l >> 3);
      const int ch = (l & 7) ^ (row & 7);
      gload16(A + (size_t)(bm + row) * a_rs + ks * 128 + ch * 16,
              As + w * 4096 + i * 1024);
      gload16(W1 + (size_t)row * w1_rs + ks * 128 + ch * 16,
              Bs + w * 4096 + i * 1024);
    }
    __syncthreads();
#pragma unroll
    for (int k0 = 0; k0 < 2; ++k0) {
      bf16x8 af[4], bff[4];
#pragma unroll
      for (int mi = 0; mi < 4; ++mi) {
        const int r = wr * 64 + mi * 16 + (l & 15);
        const int off = (k0 * 64 + (l >> 4) * 16) ^ ((r & 7) << 4);
        af[mi] = *(const bf16x8*)(As + r * 128 + off);
      }
#pragma unroll
      for (int ni = 0; ni < 4; ++ni) {
        const int r = wc * 64 + ni * 16 + (l & 15);
        const int off = (k0 * 64 + (l >> 4) * 16) ^ ((r & 7) << 4);
        bff[ni] = *(const bf16x8*)(Bs + r * 128 + off);
      }
#pragma unroll
      for (int mi = 0; mi < 4; ++mi)
#pragma unroll
        for (int ni = 0; ni < 4; ++ni)
          acc[mi][ni] = __builtin_amdgcn_mfma_f32_16x16x32_bf16(
              af[mi], bff[ni], acc[mi][ni], 0, 0, 0);
    }
    __syncthreads();
  }
  // X -> H (bf16, swizzled rows of 256 B)
#pragma unroll
  for (int mi = 0; mi < 4; ++mi)
#pragma unroll
    for (int j = 0; j < 4; ++j) {
      const int rl = wr * 64 + mi * 16 + (l >> 4) * 4 + j;
#pragma unroll
      for (int ni = 0; ni < 4; ++ni) {
        const int col = wc * 64 + ni * 16 + (l & 15);
        float v = acc[mi][ni][j] + b1[col];
        if (relu1) v = fmaxf(v, 0.f);
        const int off = (col * 2) ^ ((rl & 7) << 4);
        *(unsigned short*)(H + rl * 256 + off) = f2bf(v);
      }
    }
  // phase B: OUT_ny = X @ W2_ny^T + b2_ny
  for (int ny = 0; ny < NY; ++ny) {
    f32x4 acc2[4][4];
#pragma unroll
    for (int mi = 0; mi < 4; ++mi)
#pragma unroll
      for (int ni = 0; ni < 4; ++ni)
#pragma unroll
        for (int j = 0; j < 4; ++j) acc2[mi][ni][j] = 0.f;
    for (int ks = 0; ks < 2; ++ks) {
#pragma unroll
      for (int i = 0; i < 4; ++i) {
        const int row = w * 32 + i * 8 + (l >> 3);
        const int ch = (l & 7) ^ (row & 7);
        gload16(W2 + (size_t)(ny * 128 + row) * 256 + ks * 128 + ch * 16,
                Bs + w * 4096 + i * 1024);
      }
      __syncthreads();   // also guarantees H writes are visible (ny=0,ks=0)
#pragma unroll
      for (int k0 = 0; k0 < 2; ++k0) {
        bf16x8 af[4], bff[4];
#pragma unroll
        for (int mi = 0; mi < 4; ++mi) {
          const int r = wr * 64 + mi * 16 + (l & 15);
          const int off = (ks * 128 + k0 * 64 + (l >> 4) * 16) ^ ((r & 7) << 4);
          af[mi] = *(const bf16x8*)(H + r * 256 + off);
        }
#pragma unroll
        for (int ni = 0; ni < 4; ++ni) {
          const int r = wc * 64 + ni * 16 + (l & 15);
          const int off = (k0 * 64 + (l >> 4) * 16) ^ ((r & 7) << 4);
          bff[ni] = *(const bf16x8*)(Bs + r * 128 + off);
        }
#pragma unroll
        for (int mi = 0; mi < 4; ++mi)
#pragma unroll
          for (int ni = 0; ni < 4; ++ni)
            acc2[mi][ni] = __builtin_amdgcn_mfma_f32_16x16x32_bf16(
                af[mi], bff[ni], acc2[mi][ni], 0, 0, 0);
      }
      __syncthreads();
    }
    unsigned short* Cw = C + (size_t)ny * seg;
#pragma unroll
    for (int ni = 0; ni < 4; ++ni) {
      const int lc = wc * 64 + ni * 16 + (l & 15);
      const float bz = b2[ny * 128 + lc];
#pragma unroll
      for (int mi = 0; mi < 4; ++mi)
#pragma unroll
        for (int j = 0; j < 4; ++j) {
          const int row = bm + wr * 64 + mi * 16 + (l >> 4) * 4 + j;
          Cw[(size_t)row * c_rs + lc] = f2bf(acc2[mi][ni][j] + bz);
        }
    }
  }
}

// ---------------------------------------------------------------------------
// Attention, planar Q/K/V [N][128] bf16. Quad-parallel, 8 neighbors/iter.
// Score dot via v_dot2_f32_bf16 when available (fp32 accumulate, exact).
// Softmax unshifted (exact; scores O(1)). Quad partials via xor-16/32.
// ---------------------------------------------------------------------------
__global__ __launch_bounds__(256) void attn_kernel(
    const unsigned short* __restrict__ Q, const unsigned short* __restrict__ K,
    const unsigned short* __restrict__ V, const int* __restrict__ ctx,
    const int* __restrict__ lengths, unsigned short* __restrict__ O) {
  const int t = threadIdx.x, w = t >> 6, lane = t & 63;
  const int node = blockIdx.x * 4 + w;
  const int q4 = lane >> 4, s = lane & 15;
  const int len = lengths[node];
  const int idxv = ctx[(size_t)node * LL + (lane < LL ? lane : 0)];
  const bf16x8 qv = *(const bf16x8*)(Q + (size_t)node * 128 + s * 8);
  const float SC = 0.17677669529663687f;  // 1/sqrt(32)
#if !USE_DOT2
  float qf[8];
#pragma unroll
  for (int j = 0; j < 8; ++j) qf[j] = bf2f((unsigned short)qv[j]);
#endif
  float av[8];
#pragma unroll
  for (int j = 0; j < 8; ++j) av[j] = 0.f;
  float ssum = 0.f;

  int ok0 = q4 < len, ok1 = q4 + 4 < len;
  int ki0 = __shfl(idxv, ok0 ? q4 : 0);
  int ki1 = __shfl(idxv, ok1 ? q4 + 4 : 0);
  bf16x8 kv0 = *(const bf16x8*)(K + (size_t)ki0 * 128 + s * 8);
  bf16x8 vv0 = *(const bf16x8*)(V + (size_t)ki0 * 128 + s * 8);
  bf16x8 kv1 = *(const bf16x8*)(K + (size_t)ki1 * 128 + s * 8);
  bf16x8 vv1 = *(const bf16x8*)(V + (size_t)ki1 * 128 + s * 8);

  for (int l0 = 0; l0 < len; l0 += 8) {
    const int n0 = l0 + 8 + q4, n1 = l0 + 12 + q4;
    const int okn0 = n0 < len, okn1 = n1 < len;
    const int kin0 = __shfl(idxv, okn0 ? n0 : 0);
    const int kin1 = __shfl(idxv, okn1 ? n1 : 0);
    bf16x8 kvn0 = kv0, vvn0 = vv0, kvn1 = kv1, vvn1 = vv1;
    if (l0 + 8 < len) {
      kvn0 = *(const bf16x8*)(K + (size_t)kin0 * 128 + s * 8);
      vvn0 = *(const bf16x8*)(V + (size_t)kin0 * 128 + s * 8);
      kvn1 = *(const bf16x8*)(K + (size_t)kin1 * 128 + s * 8);
      vvn1 = *(const bf16x8*)(V + (size_t)kin1 * 128 + s * 8);
    }
    float sc0 = 0.f, sc1 = 0.f;
#if USE_DOT2
    {
      const bf2_t* qp = (const bf2_t*)&qv;
      const bf2_t* k0p = (const bf2_t*)&kv0;
      const bf2_t* k1p = (const bf2_t*)&kv1;
#pragma unroll
      for (int j = 0; j < 4; ++j) {
        sc0 = __builtin_amdgcn_fdot2_f32_bf16(qp[j], k0p[j], sc0, false);
        sc1 = __builtin_amdgcn_fdot2_f32_bf16(qp[j], k1p[j], sc1, false);
      }
    }
#else
#pragma unroll
    for (int j = 0; j < 8; ++j) {
      sc0 = fmaf(qf[j], bf2f((unsigned short)kv0[j]), sc0);
      sc1 = fmaf(qf[j], bf2f((unsigned short)kv1[j]), sc1);
    }
#endif
    sc0 += __shfl_xor(sc0, 1);
    sc0 += __shfl_xor(sc0, 2);
    sc1 += __shfl_xor(sc1, 1);
    sc1 += __shfl_xor(sc1, 2);
    const float e0 = ok0 ? __expf(sc0 * SC) : 0.f;
    const float e1 = ok1 ? __expf(sc1 * SC) : 0.f;
    ssum += e0 + e1;
#pragma unroll
    for (int j = 0; j < 8; ++j) {
      av[j] = fmaf(e0, bf2f((unsigned short)vv0[j]), av[j]);
      av[j] = fmaf(e1, bf2f((unsigned short)vv1[j]), av[j]);
    }
    kv0 = kvn0; vv0 = vvn0; kv1 = kvn1; vv1 = vvn1;
    ok0 = okn0; ok1 = okn1;
  }
  // combine the 4 quads (lane bits 4,5)
#pragma unroll
  for (int j = 0; j < 8; ++j) {
    av[j] += __shfl_xor(av[j], 16);
    av[j] += __shfl_xor(av[j], 32);
  }
  ssum += __shfl_xor(ssum, 16);
  ssum += __shfl_xor(ssum, 32);
  if (q4 == 0) {
    const float inv = 1.f / ssum;
    unsigned int o[4];
#pragma unroll
    for (int p = 0; p < 4; ++p)
      o[p] = (unsigned int)f2bf(av[2 * p] * inv) |
             ((unsigned int)f2bf(av[2 * p + 1] * inv) << 16);
    *(uint4*)(O + (size_t)node * DD + s * 8) =
        make_uint4(o[0], o[1], o[2], o[3]);
  }
}

// ---------------------------------------------------------------------------
// Fused edge MLP, 128 edges/block, all-MFMA (unchanged).
// ---------------------------------------------------------------------------
__global__ __launch_bounds__(256) void edge_fused(
    const char* __restrict__ xbf, const int* __restrict__ eu,
    const int* __restrict__ ev, const float* __restrict__ ef,
    const char* __restrict__ w1x, const float* __restrict__ w1f,
    const float* __restrict__ b1, const char* __restrict__ w2,
    const float* __restrict__ b2, const float* __restrict__ w3,
    const float* __restrict__ b3, float* __restrict__ out) {
  __shared__ char lds[65536];
  char* As = lds;
  char* Bs = lds + 16384;
  char* H1 = lds + 32768;
  float* s_part = (float*)lds;
  const int t = threadIdx.x, l = t & 63, w = t >> 6;
  const int bm = blockIdx.x * 128;
  const int wr = w >> 1, wc = w & 1;
  f32x4 acc[4][4];
#pragma unroll
  for (int mi = 0; mi < 4; ++mi)
#pragma unroll
    for (int ni = 0; ni < 4; ++ni)
#pragma unroll
      for (int j = 0; j < 4; ++j) acc[mi][ni][j] = 0.f;

  for (int ks = 0; ks < 4; ++ks) {
    const int* idxp = (ks < 2) ? eu : ev;
#pragma unroll
    for (int i = 0; i < 4; ++i) {
      const int row = w * 32 + i * 8 + (l >> 3);
      const int ch = (l & 7) ^ (row & 7);
      const int nidx = idxp[bm + row];
      gload16(xbf + (size_t)nidx * 256 + (ks & 1) * 128 + ch * 16,
              As + w * 4096 + i * 1024);
      gload16(w1x + (size_t)row * 512 + ks * 128 + ch * 16,
              Bs + w * 4096 + i * 1024);
    }
    __syncthreads();
#pragma unroll
    for (int k0 = 0; k0 < 2; ++k0) {
      bf16x8 af[4], bff[4];
#pragma unroll
      for (int mi = 0; mi < 4; ++mi) {
        const int r = wr * 64 + mi * 16 + (l & 15);
        const int off = (k0 * 64 + (l >> 4) * 16) ^ ((r & 7) << 4);
        af[mi] = *(const bf16x8*)(As + r * 128 + off);
      }
#pragma unroll
      for (int ni = 0; ni < 4; ++ni) {
        const int r = wc * 64 + ni * 16 + (l & 15);
        const int off = (k0 * 64 + (l >> 4) * 16) ^ ((r & 7) << 4);
        bff[ni] = *(const bf16x8*)(Bs + r * 128 + off);
      }
#pragma unroll
      for (int mi = 0; mi < 4; ++mi)
#pragma unroll
        for (int ni = 0; ni < 4; ++ni)
          acc[mi][ni] = __builtin_amdgcn_mfma_f32_16x16x32_bf16(
              af[mi], bff[ni], acc[mi][ni], 0, 0, 0);
    }
    __syncthreads();
  }
  float w1c0[4], w1c1[4], bb[4];
#pragma unroll
  for (int ni = 0; ni < 4; ++ni) {
    const int col = wc * 64 + ni * 16 + (l & 15);
    w1c0[ni] = w1f[col * 258 + 256];
    w1c1[ni] = w1f[col * 258 + 257];
    bb[ni] = b1[col];
  }
#pragma unroll
  for (int mi = 0; mi < 4; ++mi)
#pragma unroll
    for (int j = 0; j < 4; ++j) {
      const int rl = wr * 64 + mi * 16 + (l >> 4) * 4 + j;
      const float2 e2 = *(const float2*)(ef + 2 * (size_t)(bm + rl));
#pragma unroll
      for (int ni = 0; ni < 4; ++ni) {
        float v = acc[mi][ni][j] + e2.x * w1c0[ni] + e2.y * w1c1[ni] + bb[ni];
        v = fmaxf(v, 0.f);
        const int col = wc * 64 + ni * 16 + (l & 15);
        const int off = (col * 2) ^ ((rl & 7) << 4);
        *(unsigned short*)(H1 + rl * 256 + off) = f2bf(v);
      }
    }
  __syncthreads();
  f32x4 acc2[4][4];
#pragma unroll
  for (int mi = 0; mi < 4; ++mi)
#pragma unroll
    for (int ni = 0; ni < 4; ++ni)
#pragma unroll
      for (int j = 0; j < 4; ++j) acc2[mi][ni][j] = 0.f;
  for (int ks2 = 0; ks2 < 2; ++ks2) {
#pragma unroll
    for (int i = 0; i < 4; ++i) {
      const int row = w * 32 + i * 8 + (l >> 3);
      const int ch = (l & 7) ^ (row & 7);
      gload16(w2 + (size_t)row * 256 + ks2 * 128 + ch * 16,
              Bs + w * 4096 + i * 1024);
    }
    __syncthreads();
#pragma unroll
    for (int k0 = 0; k0 < 2; ++k0) {
      bf16x8 af[4], bff[4];
#pragma unroll
      for (int mi = 0; mi < 4; ++mi) {
        const int r = wr * 64 + mi * 16 + (l & 15);
        const int off = (ks2 * 128 + k0 * 64 + (l >> 4) * 16) ^ ((r & 7) << 4);
        af[mi] = *(const bf16x8*)(H1 + r * 256 + off);
      }
#pragma unroll
      for (int ni = 0; ni < 4; ++ni) {
        const int r = wc * 64 + ni * 16 + (l & 15);
        const int off = (k0 * 64 + (l >> 4) * 16) ^ ((r & 7) << 4);
        bff[ni] = *(const bf16x8*)(Bs + r * 128 + off);
      }
#pragma unroll
      for (int mi = 0; mi < 4; ++mi)
#pragma unroll
        for (int ni = 0; ni < 4; ++ni)
          acc2[mi][ni] = __builtin_amdgcn_mfma_f32_16x16x32_bf16(
              af[mi], bff[ni], acc2[mi][ni], 0, 0, 0);
    }
    __syncthreads();
  }
  float b2v[4], w3v[4];
#pragma unroll
  for (int ni = 0; ni < 4; ++ni) {
    const int col = wc * 64 + ni * 16 + (l & 15);
    b2v[ni] = b2[col];
    w3v[ni] = w3[col];
  }
#pragma unroll
  for (int mi = 0; mi < 4; ++mi)
#pragma unroll
    for (int j = 0; j < 4; ++j) {
      const int rl = wr * 64 + mi * 16 + (l >> 4) * 4 + j;
      float p = 0.f;
#pragma unroll
      for (int ni = 0; ni < 4; ++ni) {
        const float h2 = fmaxf(acc2[mi][ni][j] + b2v[ni], 0.f);
        p = fmaf(h2, w3v[ni], p);
      }
      p += __shfl_xor(p, 1);
      p += __shfl_xor(p, 2);
      p += __shfl_xor(p, 4);
      p += __shfl_xor(p, 8);
      if ((l & 15) == 0) s_part[wc * 128 + rl] = p;
    }
  __syncthreads();
  if (t < 128) out[bm + t] = s_part[t] + s_part[128 + t] + b3[0];
}

// ---------------------------------------------------------------------------
extern "C" void kernel_launch(void* const* d_in, const int* in_sizes, int n_in,
                              void* d_out, int out_size, void* d_ws, size_t ws_size,
                              hipStream_t stream) {
  (void)in_sizes; (void)n_in; (void)out_size; (void)ws_size;
  const int*   type_idx   = (const int*)d_in[0];
  const int*   cat_idx    = (const int*)d_in[1];
  const float* log_degree = (const float*)d_in[2];
  const int*   ctx        = (const int*)d_in[3];
  const unsigned char* mask = (const unsigned char*)d_in[4];
  const int*   eu         = (const int*)d_in[5];
  const int*   ev         = (const int*)d_in[6];
  const float* ef         = (const float*)d_in[7];
  const float* type_embed = (const float*)d_in[8];
  const float* cat0       = (const float*)d_in[9];
  const float* cat1       = (const float*)d_in[10];
  const float* dw         = (const float*)d_in[11];
  const float* db         = (const float*)d_in[12];
  const float* proj_w     = (const float*)d_in[13];
  const float* proj_b     = (const float*)d_in[14];
  const float* qkv_w      = (const float*)d_in[15];
  const float* qkv_b      = (const float*)d_in[16];
  const float* out_w      = (const float*)d_in[17];
  const float* out_b      = (const float*)d_in[18];
  const float* w1         = (const float*)d_in[19];
  const float* b1         = (const float*)d_in[20];
  const float* w2         = (const float*)d_in[21];
  const float* b2         = (const float*)d_in[22];
  const float* w3         = (const float*)d_in[23];
  const float* b3         = (const float*)d_in[24];

  char* ws = (char*)d_ws;
  char* xbf     = ws;                       // [N][128] bf16   8 MB
  char* qkvbf   = ws + 8388608;             // [3][N][128] bf16 24 MB (planar)
  char* obf     = ws + 33554432;            // [N][128] bf16   8 MB
  char* featbf  = ws + 41943040;            // [N][192] bf16   12 MB
  char* qkvwbf  = ws + 54525952;            // 3*384*128 bf16
  char* outwbf  = ws + 54820864;            // 3*128*128 bf16
  char* projwbf = ws + 54919168;            // 128*192 bf16
  char* w1xbf   = ws + 54968320;            // 128*256 bf16
  char* w2bf    = ws + 55033856;            // 128*128 bf16
  int*  lengths = (int*)(ws + 55066624);
  int*  flag    = (int*)(ws + 55197696);

  hipMemsetAsync(flag, 0, sizeof(int), stream);
  detect_mask_kernel<<<256, 256, 0, stream>>>((const unsigned int*)mask, flag);
  lengths_kernel<<<NN / 256, 256, 0, stream>>>(mask, flag, lengths);

  prep_all<<<(NPREP + 255) / 256, 256, 0, stream>>>(
      type_idx, cat_idx, log_degree, type_embed, cat0, cat1, dw, db,
      (unsigned short*)featbf,
      qkv_w, out_w, proj_w, w1, w2,
      (unsigned short*)qkvwbf, (unsigned short*)outwbf,
      (unsigned short*)projwbf, (unsigned short*)w1xbf, (unsigned short*)w2bf);

  const size_t seg = (size_t)NN * 128;  // planar Q/K/V segment (elements)
  unsigned short* Qp = (unsigned short*)qkvbf;
  unsigned short* Kp = Qp + seg;
  unsigned short* Vp = Kp + seg;

  // encode fused: X = feat@projw^T + proj_b (no relu); QKV0 = X@Wqkv0^T + b
  dual_gemm<<<NN / 128, 256, 0, stream>>>(
      featbf, 384, projwbf, 384, proj_b, 3, 0,
      qkvwbf, qkv_b, 3, Qp, 128, seg);

  for (int layer = 0; layer < 3; ++layer) {
    attn_kernel<<<NN / 4, 256, 0, stream>>>(
        Qp, Kp, Vp, ctx, lengths, (unsigned short*)obf);
    if (layer < 2) {
      // fused: x = relu(O@Wout_l^T + b_l); QKV_{l+1} = x@Wqkv_{l+1}^T + b
      dual_gemm<<<NN / 128, 256, 0, stream>>>(
          obf, 256, outwbf + (size_t)layer * 32768, 256,
          out_b + (size_t)layer * 128, 2, 1,
          qkvwbf + (size_t)(layer + 1) * 98304,
          qkv_b + (size_t)(layer + 1) * 384, 3, Qp, 128, seg);
    } else {
      mfma_gemm<<<dim3(NN / 128, 1), 256, 0, stream>>>(
          obf, 256, outwbf + (size_t)layer * 32768, 256,
          out_b + (size_t)layer * 128, 2, 1, (unsigned short*)xbf, 128, 0);
    }
  }

  edge_fused<<<EE / 128, 256, 0, stream>>>(
      xbf, eu, ev, ef, w1xbf, w1, b1, w2bf, b2, w3, b3, (float*)d_out);
}